// Round 5
// baseline (232.840 us; speedup 1.0000x reference)
//
#include <hip/hip_runtime.h>
#include <hip/hip_bf16.h>

typedef unsigned short ushort_t;
typedef unsigned int uint_t;
typedef __attribute__((ext_vector_type(8))) short bf16x8;
typedef __attribute__((ext_vector_type(4))) float f32x4;

#define NNODE 2000
#define NB 8
#define LSEQ 12
#define HDIM 64
#define NEDGE 16000
#define NSEQ (NNODE * NB)            // 16000 sequences
#define OUT1_ELEMS (NNODE * NB * LSEQ * HDIM)   // 12,288,000
#define OUT1_BYTES (OUT1_ELEMS * 2)             // bf16: 24,576,000
#define AGG_BYTES  (OUT1_ELEMS * 2)             // bf16: 24,576,000
// LDS row stride: multiple of 8 elems (16 B) for ds_read_b128 (R17 lesson).
#define SST 72
#define LOG2E 1.4426950408889634f

// precomputed-fragment table sizes (ushort counts)
#define WFRAG_ELEMS (6 * 2 * 256 * 8)   // gat W3/b3 frags: 24576 (49,152 B)
#define G2FRAG_ELEMS (3 * 2 * 2 * 256 * 8) // gru2 Whh/Wih frags: 24576 (49,152 B)

__device__ __forceinline__ float bf1(ushort_t u) { return __uint_as_float(((uint_t)u) << 16); }
__device__ __forceinline__ ushort_t fbf(float f) {
    uint_t x = __float_as_uint(f);
    uint_t r = x + 0x7fffu + ((x >> 16) & 1u);   // RNE
    return (ushort_t)(r >> 16);
}
// rcp instead of IEEE divide: without -ffast-math, 1.f/x emits the full
// v_div_scale/fmas/fixup sequence (~10 insts). rcp is 1 inst, ~1 ulp.
__device__ __forceinline__ float sigm(float x) {
    return __builtin_amdgcn_rcpf(1.f + __expf(-x));
}
__device__ __forceinline__ float tanh_fast(float x) {
    return 2.f * __builtin_amdgcn_rcpf(1.f + __expf(-2.f * x)) - 1.f;
}

// ===========================================================================
// MFMA geometry (HW-verified R3): A[m=lane&15][k=quad*8+jj];
// B[k=ks*32+quad*8+jj][n=lane&15]; C row(M)=quad*4+reg, col(N)=lane&15.
// ===========================================================================

// ---------------------------------------------------------------------------
// MEGA kernel (R5 restructure):
//   bx 0        = CSR build (dispatched FIRST; rank-trick kills pass-2 atomics)
//   bx 1        = bf16 fragment precompute (gat wfrag + gru2 g2frag)
//   bx 2..1001  = GRU1 (NO global stores in the step loop: h-history kept in
//                 LDS HT and bulk-written once -- removes 12 per-step
//                 vmcnt(0) barrier drains per block)
//   bx 1002..5501 = alpha MLP (float4-vectorized loads)
// LDS is a union: GRU1 {H,XD,HT} / CSR {hist,dh,wsum} / alpha {m1}.
// ---------------------------------------------------------------------------
__global__ __launch_bounds__(256) void mega_kernel(
    const float* __restrict__ data, const float* __restrict__ Wih,
    const float* __restrict__ Whh, const float* __restrict__ bih,
    const float* __restrict__ bhh, ushort_t* __restrict__ out1,
    float* __restrict__ h1out,
    const int* __restrict__ edges, int* __restrict__ degree,
    int* __restrict__ rowstart, int* __restrict__ srcids,
    int* __restrict__ eids, int* __restrict__ order,
    int* __restrict__ rank_,
    const float* __restrict__ features,
    const float* __restrict__ W1, const float* __restrict__ b1,
    const float* __restrict__ W2, const float* __restrict__ b2,
    float* __restrict__ alphas,
    const float* __restrict__ W3, const float* __restrict__ b3,
    const float* __restrict__ Wih2, const float* __restrict__ Whh2,
    ushort_t* __restrict__ wfrag, ushort_t* __restrict__ g2frag)
{
    // ---- LDS union: GRU1 {H 4608 | XD 1664 | HT 24576} = 30848 B;
    //      CSR {hist 8000 | dh 256 | wsum 16}; alpha {m1 256} ----
    __shared__ __attribute__((aligned(16))) char SMEM[30848];
    ushort_t (*H)[16][SST]  = (ushort_t (*)[16][SST])SMEM;        // [2][16][72]
    float    (*XD)[26]      = (float (*)[26])(SMEM + 4608);       // [16][26]
    ushort_t (*HT)[12][64]  = (ushort_t (*)[12][64])(SMEM + 6272);// [16][12][64]
    int* hist = (int*)SMEM;                                       // [2000]
    int* dh   = (int*)(SMEM + 8000);                              // [64]
    int* wsum = (int*)(SMEM + 8256);                              // [4]
    float (*m1)[16] = (float (*)[16])SMEM;                        // [4][16]

    const int bx = blockIdx.x;
    const int tid = threadIdx.x;

    if (bx == 1) {
        // ============ fragment precompute (once per launch) =============
        // gat frags: layout [arr(6)][ks(2)][tid(256)][8 bf16], scaled by log2e
        {
            const int wv = tid >> 6, r = tid & 15, quad = (tid >> 4) & 3;
            const int n = wv * 16 + r;
#pragma unroll
            for (int ks = 0; ks < 2; ++ks) {
                ushort_t ta[8], tb[8], tc[8], ba[8], bb[8], bc[8];
#pragma unroll
                for (int jj = 0; jj < 8; ++jj) {
                    const int mt_ = (ks * 32 + quad * 8 + jj) * 64 + n;
                    float2 w2 = ((const float2*)W3)[mt_];
                    ta[jj] = fbf(w2.x * LOG2E); tb[jj] = fbf(w2.y * LOG2E);
                    tc[jj] = fbf(b3[mt_] * LOG2E);
                    const int mb_ = (64 + ks * 32 + quad * 8 + jj) * 64 + n;
                    float2 w2b = ((const float2*)W3)[mb_];
                    ba[jj] = fbf(w2b.x * LOG2E); bb[jj] = fbf(w2b.y * LOG2E);
                    bc[jj] = fbf(b3[mb_] * LOG2E);
                }
                *(uint4*)(wfrag + ((0 * 2 + ks) * 256 + tid) * 8) = *(uint4*)ta;
                *(uint4*)(wfrag + ((1 * 2 + ks) * 256 + tid) * 8) = *(uint4*)tb;
                *(uint4*)(wfrag + ((2 * 2 + ks) * 256 + tid) * 8) = *(uint4*)tc;
                *(uint4*)(wfrag + ((3 * 2 + ks) * 256 + tid) * 8) = *(uint4*)ba;
                *(uint4*)(wfrag + ((4 * 2 + ks) * 256 + tid) * 8) = *(uint4*)bb;
                *(uint4*)(wfrag + ((5 * 2 + ks) * 256 + tid) * 8) = *(uint4*)bc;
            }
        }
        // gru2 frags: layout [g(3)][ks(2)][which(2: 0=Bh,1=Bi)][tid(256)][8]
        {
            const int nw = tid >> 6, c = tid & 15, quad = (tid >> 4) & 3;
            const int j = nw * 16 + c;
#pragma unroll
            for (int g = 0; g < 3; ++g) {
                const int row = g * 64 + j;
#pragma unroll
                for (int ks = 0; ks < 2; ++ks) {
                    const float* wp = Whh2 + (row << 6) + ks * 32 + quad * 8;
                    float4 wa = *(const float4*)wp;
                    float4 wb = *(const float4*)(wp + 4);
                    ushort_t tmp[8];
                    tmp[0] = fbf(wa.x); tmp[1] = fbf(wa.y); tmp[2] = fbf(wa.z); tmp[3] = fbf(wa.w);
                    tmp[4] = fbf(wb.x); tmp[5] = fbf(wb.y); tmp[6] = fbf(wb.z); tmp[7] = fbf(wb.w);
                    *(uint4*)(g2frag + (((g * 2 + ks) * 2 + 0) * 256 + tid) * 8) = *(uint4*)tmp;
                    const float* wp2 = Wih2 + (row << 6) + ks * 32 + quad * 8;
                    float4 va = *(const float4*)wp2;
                    float4 vb = *(const float4*)(wp2 + 4);
                    tmp[0] = fbf(va.x); tmp[1] = fbf(va.y); tmp[2] = fbf(va.z); tmp[3] = fbf(va.w);
                    tmp[4] = fbf(vb.x); tmp[5] = fbf(vb.y); tmp[6] = fbf(vb.z); tmp[7] = fbf(vb.w);
                    *(uint4*)(g2frag + (((g * 2 + ks) * 2 + 1) * 256 + tid) * 8) = *(uint4*)tmp;
                }
            }
        }
        return;
    }

    if (bx == 0) {
        // ========== CSR build (single block; pass-2 atomics removed via
        //            rank-trick: rank_[e] = atomicAdd return from pass 1) ====
        for (int k = tid; k < NNODE; k += 256) hist[k] = 0;
        if (tid < 64) dh[tid] = 0;
        __syncthreads();
        for (int it = 0; it < 16; ++it) {
            const int e0 = it * 1024 + tid * 4;
            if (e0 + 3 < NEDGE) {
                int4 v4 = *(const int4*)(edges + NEDGE + e0);
                int4 rk;
                rk.x = atomicAdd(&hist[v4.x], 1);
                rk.y = atomicAdd(&hist[v4.y], 1);
                rk.z = atomicAdd(&hist[v4.z], 1);
                rk.w = atomicAdd(&hist[v4.w], 1);
                *(int4*)(rank_ + e0) = rk;
            } else {
#pragma unroll
                for (int k = 0; k < 4; ++k) {
                    const int e = e0 + k;
                    if (e < NEDGE) rank_[e] = atomicAdd(&hist[edges[NEDGE + e]], 1);
                }
            }
        }
        __syncthreads();
        const int lane = tid & 63, w = tid >> 6;
        int d[8];
        int s = 0;
#pragma unroll
        for (int q = 0; q < 8; ++q) {
            const int idx = tid * 8 + q;
            d[q] = (idx < NNODE) ? hist[idx] : 0;
            s += d[q];
        }
        int v = s;
#pragma unroll
        for (int off = 1; off < 64; off <<= 1) {
            int u = __shfl_up(v, off);
            if (lane >= off) v += u;
        }
        if (lane == 63) wsum[w] = v;
        __syncthreads();
        int base = 0;
        for (int k = 0; k < 4; ++k) if (k < w) base += wsum[k];
        int run = base + v - s;
        int rs8[8];
#pragma unroll
        for (int q = 0; q < 8; ++q) {
            const int idx = tid * 8 + q;
            if (idx < NNODE) {
                rs8[q] = run;
                rowstart[idx] = run;
                degree[idx] = d[q];
                run += d[q];
                atomicAdd(&dh[63 - min(d[q], 63)], 1);   // descending-degree key
            }
        }
        __syncthreads();
        if (tid == 0) {          // serial prefix over 64 buckets
            int acc = 0;
            for (int k = 0; k < 64; ++k) { const int c = dh[k]; dh[k] = acc; acc += c; }
        }
        __syncthreads();
        // scatter nodes into order[] (longest first)
#pragma unroll
        for (int q = 0; q < 8; ++q) {
            const int idx = tid * 8 + q;
            if (idx < NNODE) {
                const int pos = atomicAdd(&dh[63 - min(d[q], 63)], 1);
                order[pos] = idx;
            }
        }
        // replace hist with rowstart values (read-only in pass 2)
        __syncthreads();
#pragma unroll
        for (int q = 0; q < 8; ++q) {
            const int idx = tid * 8 + q;
            if (idx < NNODE) hist[idx] = rs8[q];
        }
        __syncthreads();
        // pass 2: atomic-free scatter, pos = rowstart[dst] + rank[e]
        for (int it = 0; it < 16; ++it) {
            const int e0 = it * 1024 + tid * 4;
            if (e0 + 3 < NEDGE) {
                int4 dv4 = *(const int4*)(edges + NEDGE + e0);
                int4 sv4 = *(const int4*)(edges + e0);
                int4 rk4 = *(const int4*)(rank_ + e0);
                int pos;
                pos = hist[dv4.x] + rk4.x; srcids[pos] = sv4.x; eids[pos] = e0;
                pos = hist[dv4.y] + rk4.y; srcids[pos] = sv4.y; eids[pos] = e0 + 1;
                pos = hist[dv4.z] + rk4.z; srcids[pos] = sv4.z; eids[pos] = e0 + 2;
                pos = hist[dv4.w] + rk4.w; srcids[pos] = sv4.w; eids[pos] = e0 + 3;
            } else {
#pragma unroll
                for (int k = 0; k < 4; ++k) {
                    const int e = e0 + k;
                    if (e < NEDGE) {
                        const int pos = hist[edges[NEDGE + e]] + rank_[e];
                        srcids[pos] = edges[e];
                        eids[pos] = e;
                    }
                }
            }
        }
        return;
    }

    if (bx > 1001) {
        // ============ alpha MLP (4 edges/block, float4 loads) ============
        const int w = tid >> 6, lane = tid & 63;
        const int e = (bx - 1002) * 4 + w;
        int i, j;
        if (e < NEDGE) { j = edges[e]; i = edges[NEDGE + e]; }
        else { i = j = e - NEDGE; }
        const int o = lane >> 2, q = lane & 3;
        const float* fsrc = (q < 2) ? (features + i * 64 + q * 32)
                                    : (features + j * 64 + (q - 2) * 32);
        const float* wsrc = W1 + o * 128 + q * 32;
        const float4* f4 = (const float4*)fsrc;
        const float4* w4 = (const float4*)wsrc;
        float acc = 0.f;
#pragma unroll
        for (int k = 0; k < 8; ++k) {
            float4 a = f4[k], b = w4[k];
            acc = fmaf(a.x, b.x, acc);
            acc = fmaf(a.y, b.y, acc);
            acc = fmaf(a.z, b.z, acc);
            acc = fmaf(a.w, b.w, acc);
        }
        acc += __shfl_xor(acc, 1);
        acc += __shfl_xor(acc, 2);
        if (q == 0) m1[w][o] = sigm(acc + b1[o]);
        __syncthreads();
        if (lane < 32 && e < NEDGE + NNODE) {
            const int o2 = lane >> 4, k = lane & 15;
            float p = m1[w][k] * W2[o2 * 16 + k];
            p += __shfl_xor(p, 1);
            p += __shfl_xor(p, 2);
            p += __shfl_xor(p, 4);
            p += __shfl_xor(p, 8);
            if (k == 0) alphas[e * 2 + o2] = sigm(p + b2[o2]);
        }
        return;
    }

    // ================= GRU1 (blocks 2..1001) =================
    const int nw = tid >> 6;
    const int c = tid & 15;
    const int quad = (tid >> 4) & 3;
    const int j = nw * 16 + c;
    const int s0 = (bx - 2) * 16;

    if (tid < 128) *(uint4*)&H[0][tid >> 3][(tid & 7) * 8] = uint4{0, 0, 0, 0};
#pragma unroll
    for (int p = 0; p < 2; ++p) {
        const int flat = p * 256 + tid;
        if (flat < 384) {
            const int sl = flat / 24, q = flat - sl * 24;
            XD[sl][q] = data[(s0 + sl) * 24 + q];
        }
    }

    bf16x8 Bh[3][2];
    float wi0[3], wi1[3], bi[3], bh[3];
#pragma unroll
    for (int g = 0; g < 3; ++g) {
        const int row = g * 64 + j;
        float2 wi = *(const float2*)(Wih + row * 2);
        wi0[g] = wi.x; wi1[g] = wi.y;
        bi[g] = bih[row]; bh[g] = bhh[row];
#pragma unroll
        for (int ks = 0; ks < 2; ++ks) {
            const float* wp = Whh + (row << 6) + ks * 32 + quad * 8;
            float4 wa = *(const float4*)wp;
            float4 wb = *(const float4*)(wp + 4);
            ushort_t tmp[8];
            tmp[0] = fbf(wa.x); tmp[1] = fbf(wa.y); tmp[2] = fbf(wa.z); tmp[3] = fbf(wa.w);
            tmp[4] = fbf(wb.x); tmp[5] = fbf(wb.y); tmp[6] = fbf(wb.z); tmp[7] = fbf(wb.w);
            Bh[g][ks] = *(bf16x8*)tmp;
        }
    }

    float hold[4];
#pragma unroll
    for (int rg = 0; rg < 4; ++rg) hold[rg] = 0.f;

    for (int t = 0; t < LSEQ; ++t) {
        __syncthreads();
        const ushort_t (*Hr)[SST] = H[t & 1];
        ushort_t (*Hw)[SST] = H[1 - (t & 1)];
        bf16x8 a0 = *(const bf16x8*)&Hr[c][quad * 8];
        bf16x8 a1 = *(const bf16x8*)&Hr[c][32 + quad * 8];
        f32x4 gh[3];
#pragma unroll
        for (int g = 0; g < 3; ++g) {
            f32x4 acc = {0.f, 0.f, 0.f, 0.f};
            acc = __builtin_amdgcn_mfma_f32_16x16x32_bf16(a0, Bh[g][0], acc, 0, 0, 0);
            acc = __builtin_amdgcn_mfma_f32_16x16x32_bf16(a1, Bh[g][1], acc, 0, 0, 0);
            gh[g] = acc;
        }
#pragma unroll
        for (int rg = 0; rg < 4; ++rg) {
            const int sloc = quad * 4 + rg;
            float2 xp = *(const float2*)&XD[sloc][2 * t];
            float gr = bh[0] + gh[0][rg];
            float gz = bh[1] + gh[1][rg];
            float gn = bh[2] + gh[2][rg];
            float ir = bi[0] + wi0[0] * xp.x + wi1[0] * xp.y;
            float iz = bi[1] + wi0[1] * xp.x + wi1[1] * xp.y;
            float in = bi[2] + wi0[2] * xp.x + wi1[2] * xp.y;
            float r = sigm(ir + gr);
            float z = sigm(iz + gz);
            float n = tanh_fast(in + r * gn);
            float hv = (1.f - z) * n + z * hold[rg];
            hold[rg] = hv;
            const ushort_t hv16 = fbf(hv);
            Hw[sloc][j] = hv16;           // next-step MFMA operand
            HT[sloc][t][j] = hv16;        // history (bulk out1 write at end)
        }
    }
    __syncthreads();   // all HT writes visible
    // bulk coalesced out1 write: block region is contiguous [s0*768, +12288)
    {
        const ushort_t* HTf = &HT[0][0][0];
#pragma unroll
        for (int q = 0; q < 6; ++q) {
            const int idx8 = (q * 256 + tid) * 8;
            *(uint4*)(out1 + s0 * (LSEQ * HDIM) + idx8) = *(const uint4*)(HTf + idx8);
        }
    }
#pragma unroll
    for (int rg = 0; rg < 4; ++rg) {
        const int sloc = quad * 4 + rg;
        h1out[(s0 + sloc) * HDIM + j] = hold[rg];
    }
}

// ---------------------------------------------------------------------------
// MetaGAT (unchanged from R4): CSR, MFMA, K-split, pair-batched, 3-way node
// split; fixed-B-frag scheme; W3/b3 frags precomputed+log2e-scaled; uniform
// CSR loads software-pipelined; Sj C-position dword reads.
// ---------------------------------------------------------------------------
__global__ __launch_bounds__(256) void gat_csr_kernel(
    const ushort_t* __restrict__ out1,
    const int* __restrict__ degree, const int* __restrict__ rowstart,
    const int* __restrict__ srcids, const int* __restrict__ eids,
    const int* __restrict__ order,
    const float* __restrict__ alphas,
    const ushort_t* __restrict__ wfrag,
    ushort_t* __restrict__ agg)
{
    __shared__ ushort_t POOL[4][32][SST] __attribute__((aligned(16)));  // 18432 B

    const int tid = threadIdx.x;
    const int i = order[blockIdx.x];      // degree-descending schedule
    const int mh = blockIdx.y;            // M-third
    const int deg = degree[i];
    const int rs = rowstart[i];

    const int wv = tid >> 6;              // N-strip
    const int r = tid & 15;
    const int quad = (tid >> 4) & 3;
    const int n = wv * 16 + r;

    // self-loop alpha: issue early (uniform s_load, consumed after preamble)
    const float2 aSelf = *(const float2*)(alphas + (NEDGE + i) * 2);

    // ---- precomputed invariant offsets ----
    int glo[2], lso[2];
#pragma unroll
    for (int p = 0; p < 2; ++p) {
        const int u = p * 256 + tid;
        const int rr = u >> 4, c4 = u & 15;
        const int b = rr & 7, l = (rr >> 3) + 4 * mh;
        glo[p] = (b * 12 + l) * 64 + c4 * 4;
        lso[p] = rr * SST + c4 * 4;
    }
    int afo[2][2];
#pragma unroll
    for (int mt = 0; mt < 2; ++mt) {
        afo[mt][0] = (mt * 16 + r) * SST + quad * 8;
        afo[mt][1] = afo[mt][0] + 32;
    }
    // C-position dword base offsets (ushort units, even): rows quad*4+g2,
    // col pair n&~1. g2 strides are +SST ushorts = +36 dwords.
    int cbo[2];
#pragma unroll
    for (int mt = 0; mt < 2; ++mt)
        cbo[mt] = (mt * 16 + quad * 4) * SST + (n & ~1);
    const uint_t shamt = (n & 1) ? 0u : 16u;   // bf16 in hi/lo half of dword

    const ushort_t* pi = out1 + i * (NB * LSEQ * HDIM);
    ushort_t* const sbase = &POOL[0][0][0];
    ushort_t* const Si = sbase;           // slot 0 doubles as Si

    // ---- stage Si (slot 0) ----
#pragma unroll
    for (int p = 0; p < 2; ++p)
        *(uint2*)(Si + lso[p]) = *(const uint2*)(pi + glo[p]);

    // ---- fixed B-frags: 12 coalesced dwordx4 loads from precompute table ----
    bf16x8 WtA[2], WtB[2], WtC[2], WbA[2], WbB[2], WbC[2];
#pragma unroll
    for (int ks = 0; ks < 2; ++ks) {
        WtA[ks] = *(const bf16x8*)(wfrag + ((0 * 2 + ks) * 256 + tid) * 8);
        WtB[ks] = *(const bf16x8*)(wfrag + ((1 * 2 + ks) * 256 + tid) * 8);
        WtC[ks] = *(const bf16x8*)(wfrag + ((2 * 2 + ks) * 256 + tid) * 8);
        WbA[ks] = *(const bf16x8*)(wfrag + ((3 * 2 + ks) * 256 + tid) * 8);
        WbB[ks] = *(const bf16x8*)(wfrag + ((4 * 2 + ks) * 256 + tid) * 8);
        WbC[ks] = *(const bf16x8*)(wfrag + ((5 * 2 + ks) * 256 + tid) * 8);
    }

    __syncthreads();   // Si ready

    // ---- preamble: Si-projections PA/PB/PC ----
    f32x4 PA[2], PB[2], PC[2];
#pragma unroll
    for (int mt = 0; mt < 2; ++mt) {
        bf16x8 af0 = *(const bf16x8*)(Si + afo[mt][0]);
        bf16x8 af1 = *(const bf16x8*)(Si + afo[mt][1]);
        f32x4 pa = {0.f, 0.f, 0.f, 0.f};
        f32x4 pb = {0.f, 0.f, 0.f, 0.f};
        f32x4 pc = {0.f, 0.f, 0.f, 0.f};
        pa = __builtin_amdgcn_mfma_f32_16x16x32_bf16(af0, WtA[0], pa, 0, 0, 0);
        pa = __builtin_amdgcn_mfma_f32_16x16x32_bf16(af1, WtA[1], pa, 0, 0, 0);
        pb = __builtin_amdgcn_mfma_f32_16x16x32_bf16(af0, WtB[0], pb, 0, 0, 0);
        pb = __builtin_amdgcn_mfma_f32_16x16x32_bf16(af1, WtB[1], pb, 0, 0, 0);
        pc = __builtin_amdgcn_mfma_f32_16x16x32_bf16(af0, WtC[0], pc, 0, 0, 0);
        pc = __builtin_amdgcn_mfma_f32_16x16x32_bf16(af1, WtC[1], pc, 0, 0, 0);
        PA[mt] = pa; PB[mt] = pb; PC[mt] = pc;
    }

    float accN[2][4];
#pragma unroll
    for (int mt = 0; mt < 2; ++mt)
#pragma unroll
        for (int g2 = 0; g2 < 4; ++g2) accN[mt][g2] = 0.f;

    auto process = [&](const ushort_t* SB, float2 a01) {
#pragma unroll
        for (int mt = 0; mt < 2; ++mt) {
            bf16x8 aj0 = *(const bf16x8*)(SB + afo[mt][0]);
            bf16x8 aj1 = *(const bf16x8*)(SB + afo[mt][1]);
            // C-position Sj dwords (rows g2=0..3): ds_read2_b32-formable
            const uint_t* dp = (const uint_t*)(SB + cbo[mt]);
            uint_t d0 = dp[0], d1 = dp[36], d2 = dp[72], d3 = dp[108];
            f32x4 aA = PA[mt], aB = PB[mt], aC = PC[mt];
            aA = __builtin_amdgcn_mfma_f32_16x16x32_bf16(aj0, WbA[0], aA, 0, 0, 0);
            aA = __builtin_amdgcn_mfma_f32_16x16x32_bf16(aj1, WbA[1], aA, 0, 0, 0);
            aB = __builtin_amdgcn_mfma_f32_16x16x32_bf16(aj0, WbB[0], aB, 0, 0, 0);
            aB = __builtin_amdgcn_mfma_f32_16x16x32_bf16(aj1, WbB[1], aB, 0, 0, 0);
            aC = __builtin_amdgcn_mfma_f32_16x16x32_bf16(aj0, WbC[0], aC, 0, 0, 0);
            aC = __builtin_amdgcn_mfma_f32_16x16x32_bf16(aj1, WbC[1], aC, 0, 0, 0);
            float v[4];
            float s = 0.f;
#pragma unroll
            for (int g2 = 0; g2 < 4; ++g2) {
                // frags pre-scaled by log2e -> exp2 direct; leaky commutes
                float x = fmaf(a01.x, aA[g2], fmaf(a01.y, aB[g2], aC[g2]));
                x = fmaxf(x, 0.01f * x);       // leaky_relu
                v[g2] = __builtin_amdgcn_exp2f(x);
                s += v[g2];
            }
            s += __shfl_xor(s, 16);
            const float inv = __builtin_amdgcn_rcpf(s);
            uint_t dd[4] = {d0, d1, d2, d3};
#pragma unroll
            for (int g2 = 0; g2 < 4; ++g2) {
                const float sj = __uint_as_float((dd[g2] << shamt) & 0xFFFF0000u);
                accN[mt][g2] += v[g2] * inv * sj;
            }
        }
    };

    // ---- uniform CSR metadata pipeline (SGPR-resident) ----
    int sa_nxt = 0, sb_nxt = 0, eA1 = 0, eB1 = 0;
    float2 aA_cur = float2{0.f, 0.f}, aB_cur = float2{0.f, 0.f};
    if (deg >= 1) { const int e = eids[rs];     aA_cur = *(const float2*)(alphas + e * 2); }
    if (deg >= 2) { const int e = eids[rs + 1]; aB_cur = *(const float2*)(alphas + e * 2); }
    if (deg >= 3) { sa_nxt = srcids[rs + 2]; eA1 = eids[rs + 2]; }
    if (deg >= 4) { sb_nxt = srcids[rs + 3]; eB1 = eids[rs + 3]; }

    // ---- vector prefetch CSR edges 0,1 into registers ----
    uint2 pfA[2], pfB[2];
    {
        const ushort_t* pA = out1 + ((deg >= 1) ? srcids[rs] : 0) * (NB * LSEQ * HDIM);
        const ushort_t* pB = out1 + ((deg >= 2) ? srcids[rs + 1] : 0) * (NB * LSEQ * HDIM);
#pragma unroll
        for (int p = 0; p < 2; ++p) {
            pfA[p] = *(const uint2*)(pA + glo[p]);
            pfB[p] = *(const uint2*)(pB + glo[p]);
        }
    }

    // ---- self loop (reads slot 0 = Si) ----
    process(Si, aSelf);
    __syncthreads();   // all waves done reading Si before pair 0 overwrites it

    const int npairs = (deg + 1) >> 1;
    for (int pk = 0; pk < npairs; ++pk) {
        ushort_t* SA = sbase + (2 * (pk & 1)) * (32 * SST);
        ushort_t* SB = SA + 32 * SST;
#pragma unroll
        for (int p = 0; p < 2; ++p) {
            *(uint2*)(SA + lso[p]) = pfA[p];
            *(uint2*)(SB + lso[p]) = pfB[p];
        }
        const int base = pk * 2;
        const bool hasB = (base + 1) < deg;

        // issue next-next uniform loads: srcids/eids for pair pk+2,
        // alphas for pair pk+1 (eids loaded last iteration -> no chained stall)
        int sa_n2 = 0, sb_n2 = 0, eA2 = 0, eB2 = 0;
        if (base + 4 < deg) { sa_n2 = srcids[rs + base + 4]; eA2 = eids[rs + base + 4]; }
        if (base + 5 < deg) { sb_n2 = srcids[rs + base + 5]; eB2 = eids[rs + base + 5]; }
        float2 aA_n = float2{0.f, 0.f}, aB_n = float2{0.f, 0.f};
        if (base + 2 < deg) aA_n = *(const float2*)(alphas + eA1 * 2);
        if (base + 3 < deg) aB_n = *(const float2*)(alphas + eB1 * 2);

        __syncthreads();   // pair tiles ready (pk-1 slots fully read pre-barrier)

        // vector prefetch for edges base+2,3 (addresses from LAST iteration)
        if (base + 2 < deg) {
            const ushort_t* pA = out1 + sa_nxt * (NB * LSEQ * HDIM);
#pragma unroll
            for (int p = 0; p < 2; ++p) pfA[p] = *(const uint2*)(pA + glo[p]);
        }
        if (base + 3 < deg) {
            const ushort_t* pB = out1 + sb_nxt * (NB * LSEQ * HDIM);
#pragma unroll
            for (int p = 0; p < 2; ++p) pfB[p] = *(const uint2*)(pB + glo[p]);
        }

        process(SA, aA_cur);
        if (hasB) process(SB, aB_cur);

        // rotate pipeline registers
        aA_cur = aA_n; aB_cur = aB_n;
        sa_nxt = sa_n2; sb_nxt = sb_n2;
        eA1 = eA2; eB1 = eB2;
    }

    // single non-atomic bf16 store of this third-node's aggregate
#pragma unroll
    for (int mt = 0; mt < 2; ++mt)
#pragma unroll
        for (int g2 = 0; g2 < 4; ++g2) {
            const int gr = mh * 32 + mt * 16 + quad * 4 + g2;  // = l*8 + b
            const int b = gr & 7, l = gr >> 3;
            agg[(i * 96 + b * 12 + l) * 64 + n] = fbf(accN[mt][g2]);
        }
}

// ---------------------------------------------------------------------------
// GRU2 (R5 restructure): ALL 12 x-slices pre-staged into LDS upfront (relu'd
// at load) -- the step loop is pure LDS+MFMA+VALU, so the per-step barrier no
// longer drains an in-flight global load (12 vmcnt(0) stalls removed/block).
// 16 seqs / 4 waves per block; H ping-pong; weight frags precomputed.
// ---------------------------------------------------------------------------
__global__ __launch_bounds__(256) void gru2_kernel(
    const ushort_t* __restrict__ agg, const ushort_t* __restrict__ g2frag,
    const float* __restrict__ bih, const float* __restrict__ bhh,
    float* __restrict__ h2out)
{
    __shared__ ushort_t H[2][16][SST] __attribute__((aligned(16)));   // 4608 B
    __shared__ ushort_t XA[16][LSEQ][SST] __attribute__((aligned(16))); // 27648 B

    const int tid = threadIdx.x;
    const int nw = tid >> 6;
    const int c = tid & 15;
    const int quad = (tid >> 4) & 3;
    const int j = nw * 16 + c;
    const int s0 = blockIdx.x * 16;

    if (tid < 128) *(uint4*)&H[0][tid >> 3][(tid & 7) * 8] = uint4{0, 0, 0, 0};

    // ---- stage ALL x = relu(agg) for the block's 16 seqs (coalesced) ----
    {
        const ushort_t* src = agg + s0 * (LSEQ * HDIM);
#pragma unroll
        for (int q = 0; q < 6; ++q) {
            const int idx8 = (q * 256 + tid) * 8;
            ushort_t xr[8];
            *(uint4*)xr = *(const uint4*)(src + idx8);
            ushort_t xs[8];
#pragma unroll
            for (int qq = 0; qq < 8; ++qq) xs[qq] = (xr[qq] & 0x8000u) ? (ushort_t)0 : xr[qq];
            const int seq = idx8 / (LSEQ * HDIM);
            const int rem = idx8 - seq * (LSEQ * HDIM);
            const int t = rem >> 6, k = rem & 63;
            *(uint4*)&XA[seq][t][k] = *(uint4*)xs;
        }
    }

    bf16x8 Bh[3][2], Bi[3][2];
    float bi[3], bh[3];
#pragma unroll
    for (int g = 0; g < 3; ++g) {
        const int row = g * 64 + j;
        bi[g] = bih[row]; bh[g] = bhh[row];
#pragma unroll
        for (int ks = 0; ks < 2; ++ks) {
            Bh[g][ks] = *(const bf16x8*)(g2frag + (((g * 2 + ks) * 2 + 0) * 256 + tid) * 8);
            Bi[g][ks] = *(const bf16x8*)(g2frag + (((g * 2 + ks) * 2 + 1) * 256 + tid) * 8);
        }
    }

    float hold[4];
#pragma unroll
    for (int rg = 0; rg < 4; ++rg) hold[rg] = 0.f;

    for (int t = 0; t < LSEQ; ++t) {
        __syncthreads();
        const int rb = t & 1, wb = 1 - rb;
        bf16x8 ah0 = *(const bf16x8*)&H[rb][c][quad * 8];
        bf16x8 ah1 = *(const bf16x8*)&H[rb][c][32 + quad * 8];
        bf16x8 ax0 = *(const bf16x8*)&XA[c][t][quad * 8];
        bf16x8 ax1 = *(const bf16x8*)&XA[c][t][32 + quad * 8];

        f32x4 gh[3], gi[3];
#pragma unroll
        for (int g = 0; g < 3; ++g) {
            f32x4 acc = {0.f, 0.f, 0.f, 0.f};
            acc = __builtin_amdgcn_mfma_f32_16x16x32_bf16(ah0, Bh[g][0], acc, 0, 0, 0);
            acc = __builtin_amdgcn_mfma_f32_16x16x32_bf16(ah1, Bh[g][1], acc, 0, 0, 0);
            gh[g] = acc;
            f32x4 acc2 = {0.f, 0.f, 0.f, 0.f};
            acc2 = __builtin_amdgcn_mfma_f32_16x16x32_bf16(ax0, Bi[g][0], acc2, 0, 0, 0);
            acc2 = __builtin_amdgcn_mfma_f32_16x16x32_bf16(ax1, Bi[g][1], acc2, 0, 0, 0);
            gi[g] = acc2;
        }
#pragma unroll
        for (int rg = 0; rg < 4; ++rg) {
            const int sloc = quad * 4 + rg;
            float r = sigm(bi[0] + gi[0][rg] + bh[0] + gh[0][rg]);
            float z = sigm(bi[1] + gi[1][rg] + bh[1] + gh[1][rg]);
            float n = tanh_fast(bi[2] + gi[2][rg] + r * (bh[2] + gh[2][rg]));
            float hv = (1.f - z) * n + z * hold[rg];
            hold[rg] = hv;
            H[wb][sloc][j] = fbf(hv);
        }
    }
#pragma unroll
    for (int rg = 0; rg < 4; ++rg) {
        const int sloc = quad * 4 + rg;
        h2out[(s0 + sloc) * HDIM + j] = hold[rg];
    }
}

extern "C" void kernel_launch(void* const* d_in, const int* in_sizes, int n_in,
                              void* d_out, int out_size, void* d_ws, size_t ws_size,
                              hipStream_t stream)
{
    const float* data     = (const float*)d_in[0];
    const float* features = (const float*)d_in[1];
    const int*   edges    = (const int*)d_in[2];
    const float* Wih1     = (const float*)d_in[3];
    const float* Whh1     = (const float*)d_in[4];
    const float* bih1     = (const float*)d_in[5];
    const float* bhh1     = (const float*)d_in[6];
    const float* W1       = (const float*)d_in[7];
    const float* b1       = (const float*)d_in[8];
    const float* W2       = (const float*)d_in[9];
    const float* b2       = (const float*)d_in[10];
    const float* W3       = (const float*)d_in[11];
    const float* b3       = (const float*)d_in[12];
    const float* Wih2     = (const float*)d_in[13];
    const float* Whh2     = (const float*)d_in[14];
    const float* bih2     = (const float*)d_in[15];
    const float* bhh2     = (const float*)d_in[16];

    float*    out  = (float*)d_out;
    char*     ws   = (char*)d_ws;
    ushort_t* out1 = (ushort_t*)ws;                    // bf16 intermediate
    ushort_t* agg  = (ushort_t*)(ws + OUT1_BYTES);     // bf16 GAT output
    int*      meta = (int*)(ws + OUT1_BYTES + AGG_BYTES);
    int*   degree   = meta;                                 // [2000]
    int*   rowstart = meta + NNODE;                         // [2000]
    int*   srcids   = meta + 2 * NNODE;                     // [16000]
    int*   eids     = meta + 2 * NNODE + NEDGE;             // [16000]
    int*   order    = meta + 2 * NNODE + 2 * NEDGE;         // [2000]
    float* alphas   = (float*)(meta + 3 * NNODE + 2 * NEDGE);  // [36000]
    ushort_t* wfrag  = (ushort_t*)((char*)alphas + 36000 * 4); // [24576] 16B-aligned
    ushort_t* g2frag = wfrag + WFRAG_ELEMS;                    // [24576]
    int*      rank_  = (int*)(g2frag + G2FRAG_ELEMS);          // [16000]

    // 3 dispatches: mega (csr || frag || gru1 || alpha), gat, gru2.
    mega_kernel<<<5502, 256, 0, stream>>>(
        data, Wih1, Whh1, bih1, bhh1, out1, out,
        edges, degree, rowstart, srcids, eids, order, rank_,
        features, W1, b1, W2, b2, alphas,
        W3, b3, Wih2, Whh2, wfrag, g2frag);
    gat_csr_kernel<<<dim3(NNODE, 3), 256, 0, stream>>>(out1, degree, rowstart, srcids,
                                                       eids, order, alphas, wfrag, agg);
    gru2_kernel<<<NSEQ / 16, 256, 0, stream>>>(agg, g2frag, bih2, bhh2,
                                               out + NNODE * NB * HDIM);
}

// Round 6
// 230.681 us; speedup vs baseline: 1.0094x; 1.0094x over previous
//
#include <hip/hip_runtime.h>
#include <hip/hip_bf16.h>

typedef unsigned short ushort_t;
typedef unsigned int uint_t;
typedef __attribute__((ext_vector_type(8))) short bf16x8;
typedef __attribute__((ext_vector_type(4))) float f32x4;

#define NNODE 2000
#define NB 8
#define LSEQ 12
#define HDIM 64
#define NEDGE 16000
#define NSEQ (NNODE * NB)            // 16000 sequences
#define OUT1_ELEMS (NNODE * NB * LSEQ * HDIM)   // 12,288,000
#define OUT1_BYTES (OUT1_ELEMS * 2)             // bf16: 24,576,000
#define AGG_BYTES  (OUT1_ELEMS * 2)             // bf16: 24,576,000
// LDS row stride: multiple of 8 elems (16 B) for ds_read_b128 (R17 lesson).
#define SST 72
#define LOG2E 1.4426950408889634f

// precomputed-fragment table sizes (ushort counts)
#define WFRAG_ELEMS (6 * 2 * 256 * 8)   // gat W3/b3 frags: 24576 (49,152 B)
#define G2FRAG_ELEMS (3 * 2 * 2 * 256 * 8) // gru2 Whh/Wih frags: 24576 (49,152 B)

__device__ __forceinline__ float bf1(ushort_t u) { return __uint_as_float(((uint_t)u) << 16); }
__device__ __forceinline__ ushort_t fbf(float f) {
    uint_t x = __float_as_uint(f);
    uint_t r = x + 0x7fffu + ((x >> 16) & 1u);   // RNE
    return (ushort_t)(r >> 16);
}
// rcp instead of IEEE divide (R2 win): 1 inst vs ~10-inst div sequence.
__device__ __forceinline__ float sigm(float x) {
    return __builtin_amdgcn_rcpf(1.f + __expf(-x));
}
// log2e-folded variants: argument is PRE-SCALED by log2e (sigm2) or
// 2*log2e (tanh2) via the weight/bias tables -- saves the v_mul inside
// every __expf on the serial gate chain (same mechanism as R2's -14.7us).
__device__ __forceinline__ float sigm2(float x) {
    return __builtin_amdgcn_rcpf(1.f + __builtin_amdgcn_exp2f(-x));
}
__device__ __forceinline__ float tanh2(float x) {
    return 2.f * __builtin_amdgcn_rcpf(1.f + __builtin_amdgcn_exp2f(-x)) - 1.f;
}

// ===========================================================================
// MFMA geometry (HW-verified R3): A[m=lane&15][k=quad*8+jj];
// B[k=ks*32+quad*8+jj][n=lane&15]; C row(M)=quad*4+reg, col(N)=lane&15.
// ===========================================================================

// ---------------------------------------------------------------------------
// MEGA kernel (R4 structure, reverted from R5 regression):
//   bx 0..999    = GRU1 (log2e-folded gates)
//   bx 1000      = CSR build (int4-vectorized)
//   bx 1001..5500 = alpha MLP (float4 loads)
//   bx 5501      = bf16 fragment precompute (gat wfrag log2e-scaled;
//                  gru2 g2frag gate-row-scaled by log2e / 2log2e)
// ---------------------------------------------------------------------------
__global__ __launch_bounds__(256) void mega_kernel(
    const float* __restrict__ data, const float* __restrict__ Wih,
    const float* __restrict__ Whh, const float* __restrict__ bih,
    const float* __restrict__ bhh, ushort_t* __restrict__ out1,
    float* __restrict__ h1out,
    const int* __restrict__ edges, int* __restrict__ degree,
    int* __restrict__ rowstart, int* __restrict__ srcids,
    int* __restrict__ eids, int* __restrict__ order,
    const float* __restrict__ features,
    const float* __restrict__ W1, const float* __restrict__ b1,
    const float* __restrict__ W2, const float* __restrict__ b2,
    float* __restrict__ alphas,
    const float* __restrict__ W3, const float* __restrict__ b3,
    const float* __restrict__ Wih2, const float* __restrict__ Whh2,
    ushort_t* __restrict__ wfrag, ushort_t* __restrict__ g2frag)
{
    __shared__ ushort_t H[2][16][SST] __attribute__((aligned(16)));
    __shared__ float XD[16][26];
    __shared__ int hist[NNODE];
    __shared__ int wsum[4];
    __shared__ float m1[4][16];
    __shared__ int dh[64];

    const int bx = blockIdx.x;
    const int tid = threadIdx.x;

    if (bx == 5501) {
        // ============ fragment precompute (once per launch) =============
        // gat frags: layout [arr(6)][ks(2)][tid(256)][8 bf16], scaled by log2e
        {
            const int wv = tid >> 6, r = tid & 15, quad = (tid >> 4) & 3;
            const int n = wv * 16 + r;
#pragma unroll
            for (int ks = 0; ks < 2; ++ks) {
                ushort_t ta[8], tb[8], tc[8], ba[8], bb[8], bc[8];
#pragma unroll
                for (int jj = 0; jj < 8; ++jj) {
                    const int mt_ = (ks * 32 + quad * 8 + jj) * 64 + n;
                    float2 w2 = ((const float2*)W3)[mt_];
                    ta[jj] = fbf(w2.x * LOG2E); tb[jj] = fbf(w2.y * LOG2E);
                    tc[jj] = fbf(b3[mt_] * LOG2E);
                    const int mb_ = (64 + ks * 32 + quad * 8 + jj) * 64 + n;
                    float2 w2b = ((const float2*)W3)[mb_];
                    ba[jj] = fbf(w2b.x * LOG2E); bb[jj] = fbf(w2b.y * LOG2E);
                    bc[jj] = fbf(b3[mb_] * LOG2E);
                }
                *(uint4*)(wfrag + ((0 * 2 + ks) * 256 + tid) * 8) = *(uint4*)ta;
                *(uint4*)(wfrag + ((1 * 2 + ks) * 256 + tid) * 8) = *(uint4*)tb;
                *(uint4*)(wfrag + ((2 * 2 + ks) * 256 + tid) * 8) = *(uint4*)tc;
                *(uint4*)(wfrag + ((3 * 2 + ks) * 256 + tid) * 8) = *(uint4*)ba;
                *(uint4*)(wfrag + ((4 * 2 + ks) * 256 + tid) * 8) = *(uint4*)bb;
                *(uint4*)(wfrag + ((5 * 2 + ks) * 256 + tid) * 8) = *(uint4*)bc;
            }
        }
        // gru2 frags: [g(3)][ks(2)][which(2: 0=Bh,1=Bi)][tid(256)][8];
        // gate rows g=0,1 scaled by log2e, g=2 (n-gate) by 2*log2e.
        {
            const int nw = tid >> 6, c = tid & 15, quad = (tid >> 4) & 3;
            const int j = nw * 16 + c;
#pragma unroll
            for (int g = 0; g < 3; ++g) {
                const float sc = (g == 2) ? 2.f * LOG2E : LOG2E;
                const int row = g * 64 + j;
#pragma unroll
                for (int ks = 0; ks < 2; ++ks) {
                    const float* wp = Whh2 + (row << 6) + ks * 32 + quad * 8;
                    float4 wa = *(const float4*)wp;
                    float4 wb = *(const float4*)(wp + 4);
                    ushort_t tmp[8];
                    tmp[0] = fbf(wa.x * sc); tmp[1] = fbf(wa.y * sc);
                    tmp[2] = fbf(wa.z * sc); tmp[3] = fbf(wa.w * sc);
                    tmp[4] = fbf(wb.x * sc); tmp[5] = fbf(wb.y * sc);
                    tmp[6] = fbf(wb.z * sc); tmp[7] = fbf(wb.w * sc);
                    *(uint4*)(g2frag + (((g * 2 + ks) * 2 + 0) * 256 + tid) * 8) = *(uint4*)tmp;
                    const float* wp2 = Wih2 + (row << 6) + ks * 32 + quad * 8;
                    float4 va = *(const float4*)wp2;
                    float4 vb = *(const float4*)(wp2 + 4);
                    tmp[0] = fbf(va.x * sc); tmp[1] = fbf(va.y * sc);
                    tmp[2] = fbf(va.z * sc); tmp[3] = fbf(va.w * sc);
                    tmp[4] = fbf(vb.x * sc); tmp[5] = fbf(vb.y * sc);
                    tmp[6] = fbf(vb.z * sc); tmp[7] = fbf(vb.w * sc);
                    *(uint4*)(g2frag + (((g * 2 + ks) * 2 + 1) * 256 + tid) * 8) = *(uint4*)tmp;
                }
            }
        }
        return;
    }

    if (bx == 1000) {
        // ========== CSR build (single block, int4-vectorized loads) ========
        for (int k = tid; k < NNODE; k += 256) hist[k] = 0;
        if (tid < 64) dh[tid] = 0;
        __syncthreads();
        for (int it = 0; it < 16; ++it) {
            const int e0 = it * 1024 + tid * 4;
            if (e0 + 3 < NEDGE) {
                int4 v4 = *(const int4*)(edges + NEDGE + e0);
                atomicAdd(&hist[v4.x], 1);
                atomicAdd(&hist[v4.y], 1);
                atomicAdd(&hist[v4.z], 1);
                atomicAdd(&hist[v4.w], 1);
            } else {
#pragma unroll
                for (int k = 0; k < 4; ++k) {
                    const int e = e0 + k;
                    if (e < NEDGE) atomicAdd(&hist[edges[NEDGE + e]], 1);
                }
            }
        }
        __syncthreads();
        const int lane = tid & 63, w = tid >> 6;
        int d[8];
        int s = 0;
#pragma unroll
        for (int q = 0; q < 8; ++q) {
            const int idx = tid * 8 + q;
            d[q] = (idx < NNODE) ? hist[idx] : 0;
            s += d[q];
        }
        int v = s;
#pragma unroll
        for (int off = 1; off < 64; off <<= 1) {
            int u = __shfl_up(v, off);
            if (lane >= off) v += u;
        }
        if (lane == 63) wsum[w] = v;
        __syncthreads();
        int base = 0;
        for (int k = 0; k < 4; ++k) if (k < w) base += wsum[k];
        int run = base + v - s;
        int rs8[8];
#pragma unroll
        for (int q = 0; q < 8; ++q) {
            const int idx = tid * 8 + q;
            if (idx < NNODE) {
                rs8[q] = run;
                rowstart[idx] = run;
                degree[idx] = d[q];
                run += d[q];
                atomicAdd(&dh[63 - min(d[q], 63)], 1);   // descending-degree key
            }
        }
        __syncthreads();
        if (tid == 0) {          // serial prefix over 64 buckets
            int acc = 0;
            for (int k = 0; k < 64; ++k) { const int c = dh[k]; dh[k] = acc; acc += c; }
        }
        __syncthreads();
        // scatter nodes into order[] (longest first)
#pragma unroll
        for (int q = 0; q < 8; ++q) {
            const int idx = tid * 8 + q;
            if (idx < NNODE) {
                const int pos = atomicAdd(&dh[63 - min(d[q], 63)], 1);
                order[pos] = idx;
            }
        }
        // reuse hist as scatter cursor
        __syncthreads();
#pragma unroll
        for (int q = 0; q < 8; ++q) {
            const int idx = tid * 8 + q;
            if (idx < NNODE) hist[idx] = rs8[q];
        }
        __syncthreads();
        for (int it = 0; it < 16; ++it) {
            const int e0 = it * 1024 + tid * 4;
            if (e0 + 3 < NEDGE) {
                int4 dv4 = *(const int4*)(edges + NEDGE + e0);
                int4 sv4 = *(const int4*)(edges + e0);
                int pos;
                pos = atomicAdd(&hist[dv4.x], 1); srcids[pos] = sv4.x; eids[pos] = e0;
                pos = atomicAdd(&hist[dv4.y], 1); srcids[pos] = sv4.y; eids[pos] = e0 + 1;
                pos = atomicAdd(&hist[dv4.z], 1); srcids[pos] = sv4.z; eids[pos] = e0 + 2;
                pos = atomicAdd(&hist[dv4.w], 1); srcids[pos] = sv4.w; eids[pos] = e0 + 3;
            } else {
#pragma unroll
                for (int k = 0; k < 4; ++k) {
                    const int e = e0 + k;
                    if (e < NEDGE) {
                        const int pos = atomicAdd(&hist[edges[NEDGE + e]], 1);
                        srcids[pos] = edges[e];
                        eids[pos] = e;
                    }
                }
            }
        }
        return;
    }

    if (bx > 1000) {
        // ============ alpha MLP (4 edges/block, float4 loads) ============
        const int w = tid >> 6, lane = tid & 63;
        const int e = (bx - 1001) * 4 + w;
        int i, j;
        if (e < NEDGE) { j = edges[e]; i = edges[NEDGE + e]; }
        else { i = j = e - NEDGE; }
        const int o = lane >> 2, q = lane & 3;
        const float* fsrc = (q < 2) ? (features + i * 64 + q * 32)
                                    : (features + j * 64 + (q - 2) * 32);
        const float* wsrc = W1 + o * 128 + q * 32;
        const float4* f4 = (const float4*)fsrc;
        const float4* w4 = (const float4*)wsrc;
        float acc = 0.f;
#pragma unroll
        for (int k = 0; k < 8; ++k) {
            float4 a = f4[k], b = w4[k];
            acc = fmaf(a.x, b.x, acc);
            acc = fmaf(a.y, b.y, acc);
            acc = fmaf(a.z, b.z, acc);
            acc = fmaf(a.w, b.w, acc);
        }
        acc += __shfl_xor(acc, 1);
        acc += __shfl_xor(acc, 2);
        if (q == 0) m1[w][o] = sigm(acc + b1[o]);
        __syncthreads();
        if (lane < 32 && e < NEDGE + NNODE) {
            const int o2 = lane >> 4, k = lane & 15;
            float p = m1[w][k] * W2[o2 * 16 + k];
            p += __shfl_xor(p, 1);
            p += __shfl_xor(p, 2);
            p += __shfl_xor(p, 4);
            p += __shfl_xor(p, 8);
            if (k == 0) alphas[e * 2 + o2] = sigm(p + b2[o2]);
        }
        return;
    }

    // ================= GRU1 (blocks 0..999), log2e-folded gates ==========
    const int nw = tid >> 6;
    const int c = tid & 15;
    const int quad = (tid >> 4) & 3;
    const int j = nw * 16 + c;
    const int s0 = bx * 16;
    const int crow = tid >> 4, ccol = (tid & 15) * 4;   // out1 copy mapping (uint2)

    if (tid < 128) *(uint4*)&H[0][tid >> 3][(tid & 7) * 8] = uint4{0, 0, 0, 0};
#pragma unroll
    for (int p = 0; p < 2; ++p) {
        const int flat = p * 256 + tid;
        if (flat < 384) {
            const int sl = flat / 24, q = flat - sl * 24;
            XD[sl][q] = data[(s0 + sl) * 24 + q];
        }
    }

    bf16x8 Bh[3][2];
    float wi0[3], wi1[3], bi[3], bh[3];
#pragma unroll
    for (int g = 0; g < 3; ++g) {
        const float sc = (g == 2) ? 2.f * LOG2E : LOG2E;   // gate pre-scaling
        const int row = g * 64 + j;
        float2 wi = *(const float2*)(Wih + row * 2);
        wi0[g] = wi.x * sc; wi1[g] = wi.y * sc;
        bi[g] = bih[row] * sc; bh[g] = bhh[row] * sc;
#pragma unroll
        for (int ks = 0; ks < 2; ++ks) {
            const float* wp = Whh + (row << 6) + ks * 32 + quad * 8;
            float4 wa = *(const float4*)wp;
            float4 wb = *(const float4*)(wp + 4);
            ushort_t tmp[8];
            tmp[0] = fbf(wa.x * sc); tmp[1] = fbf(wa.y * sc);
            tmp[2] = fbf(wa.z * sc); tmp[3] = fbf(wa.w * sc);
            tmp[4] = fbf(wb.x * sc); tmp[5] = fbf(wb.y * sc);
            tmp[6] = fbf(wb.z * sc); tmp[7] = fbf(wb.w * sc);
            Bh[g][ks] = *(bf16x8*)tmp;
        }
    }

    float hold[4];
#pragma unroll
    for (int rg = 0; rg < 4; ++rg) hold[rg] = 0.f;

    for (int t = 0; t < LSEQ; ++t) {
        __syncthreads();
        const ushort_t (*Hr)[SST] = H[t & 1];
        ushort_t (*Hw)[SST] = H[1 - (t & 1)];
        bf16x8 a0 = *(const bf16x8*)&Hr[c][quad * 8];
        bf16x8 a1 = *(const bf16x8*)&Hr[c][32 + quad * 8];
        // coalesced out1 write of h_{t-1} from the stable read buffer
        if (t > 0)
            *(uint2*)(out1 + (s0 + crow) * (LSEQ * HDIM) + (t - 1) * HDIM + ccol) =
                *(const uint2*)&Hr[crow][ccol];
        f32x4 gh[3];
#pragma unroll
        for (int g = 0; g < 3; ++g) {
            f32x4 acc = {0.f, 0.f, 0.f, 0.f};
            acc = __builtin_amdgcn_mfma_f32_16x16x32_bf16(a0, Bh[g][0], acc, 0, 0, 0);
            acc = __builtin_amdgcn_mfma_f32_16x16x32_bf16(a1, Bh[g][1], acc, 0, 0, 0);
            gh[g] = acc;
        }
#pragma unroll
        for (int rg = 0; rg < 4; ++rg) {
            const int sloc = quad * 4 + rg;
            float2 xp = *(const float2*)&XD[sloc][2 * t];
            float gr = bh[0] + gh[0][rg];
            float gz = bh[1] + gh[1][rg];
            float gn = bh[2] + gh[2][rg];
            float ir = bi[0] + wi0[0] * xp.x + wi1[0] * xp.y;
            float iz = bi[1] + wi0[1] * xp.x + wi1[1] * xp.y;
            float in = bi[2] + wi0[2] * xp.x + wi1[2] * xp.y;
            float r = sigm2(ir + gr);          // args pre-scaled by log2e
            float z = sigm2(iz + gz);
            float n = tanh2(in + r * gn);      // pre-scaled by 2*log2e
            float hv = (1.f - z) * n + z * hold[rg];
            hold[rg] = hv;
            Hw[sloc][j] = fbf(hv);
        }
    }
    __syncthreads();   // final H[LSEQ&1] (= h_{11}) complete
    *(uint2*)(out1 + (s0 + crow) * (LSEQ * HDIM) + (LSEQ - 1) * HDIM + ccol) =
        *(const uint2*)&H[LSEQ & 1][crow][ccol];
#pragma unroll
    for (int rg = 0; rg < 4; ++rg) {
        const int sloc = quad * 4 + rg;
        h1out[(s0 + sloc) * HDIM + j] = hold[rg];
    }
}

// ---------------------------------------------------------------------------
// MetaGAT (R6): same MFMA/softmax core as R4, but the out1 tile prefetch is
// now TWO pairs deep (pfE/pfO register sets) and reload is issued right
// after the ds_write, BEFORE the barrier -- each HBM/L3 tile load gets ~2
// compute phases + a barrier of latency cover instead of <1 phase.
// ---------------------------------------------------------------------------
__global__ __launch_bounds__(256) void gat_csr_kernel(
    const ushort_t* __restrict__ out1,
    const int* __restrict__ degree, const int* __restrict__ rowstart,
    const int* __restrict__ srcids, const int* __restrict__ eids,
    const int* __restrict__ order,
    const float* __restrict__ alphas,
    const ushort_t* __restrict__ wfrag,
    ushort_t* __restrict__ agg)
{
    __shared__ ushort_t POOL[4][32][SST] __attribute__((aligned(16)));  // 18432 B

    const int tid = threadIdx.x;
    const int i = order[blockIdx.x];      // degree-descending schedule
    const int mh = blockIdx.y;            // M-third
    const int deg = degree[i];
    const int rs = rowstart[i];

    const int wv = tid >> 6;              // N-strip
    const int r = tid & 15;
    const int quad = (tid >> 4) & 3;
    const int n = wv * 16 + r;

    // self-loop alpha: issue early (uniform s_load, consumed after preamble)
    const float2 aSelf = *(const float2*)(alphas + (NEDGE + i) * 2);

    // ---- precomputed invariant offsets ----
    int glo[2], lso[2];
#pragma unroll
    for (int p = 0; p < 2; ++p) {
        const int u = p * 256 + tid;
        const int rr = u >> 4, c4 = u & 15;
        const int b = rr & 7, l = (rr >> 3) + 4 * mh;
        glo[p] = (b * 12 + l) * 64 + c4 * 4;
        lso[p] = rr * SST + c4 * 4;
    }
    int afo[2][2];
#pragma unroll
    for (int mt = 0; mt < 2; ++mt) {
        afo[mt][0] = (mt * 16 + r) * SST + quad * 8;
        afo[mt][1] = afo[mt][0] + 32;
    }
    // C-position dword base offsets (ushort units, even): rows quad*4+g2,
    // col pair n&~1. g2 strides are +SST ushorts = +36 dwords.
    int cbo[2];
#pragma unroll
    for (int mt = 0; mt < 2; ++mt)
        cbo[mt] = (mt * 16 + quad * 4) * SST + (n & ~1);
    const uint_t shamt = (n & 1) ? 0u : 16u;   // bf16 in hi/lo half of dword

    const ushort_t* pi = out1 + i * (NB * LSEQ * HDIM);
    ushort_t* const sbase = &POOL[0][0][0];
    ushort_t* const Si = sbase;           // slot 0 doubles as Si

    // ---- stage Si (slot 0) ----
#pragma unroll
    for (int p = 0; p < 2; ++p)
        *(uint2*)(Si + lso[p]) = *(const uint2*)(pi + glo[p]);

    // ---- fixed B-frags: 12 coalesced dwordx4 loads from precompute table ----
    bf16x8 WtA[2], WtB[2], WtC[2], WbA[2], WbB[2], WbC[2];
#pragma unroll
    for (int ks = 0; ks < 2; ++ks) {
        WtA[ks] = *(const bf16x8*)(wfrag + ((0 * 2 + ks) * 256 + tid) * 8);
        WtB[ks] = *(const bf16x8*)(wfrag + ((1 * 2 + ks) * 256 + tid) * 8);
        WtC[ks] = *(const bf16x8*)(wfrag + ((2 * 2 + ks) * 256 + tid) * 8);
        WbA[ks] = *(const bf16x8*)(wfrag + ((3 * 2 + ks) * 256 + tid) * 8);
        WbB[ks] = *(const bf16x8*)(wfrag + ((4 * 2 + ks) * 256 + tid) * 8);
        WbC[ks] = *(const bf16x8*)(wfrag + ((5 * 2 + ks) * 256 + tid) * 8);
    }

    __syncthreads();   // Si ready

    // ---- preamble: Si-projections PA/PB/PC ----
    f32x4 PA[2], PB[2], PC[2];
#pragma unroll
    for (int mt = 0; mt < 2; ++mt) {
        bf16x8 af0 = *(const bf16x8*)(Si + afo[mt][0]);
        bf16x8 af1 = *(const bf16x8*)(Si + afo[mt][1]);
        f32x4 pa = {0.f, 0.f, 0.f, 0.f};
        f32x4 pb = {0.f, 0.f, 0.f, 0.f};
        f32x4 pc = {0.f, 0.f, 0.f, 0.f};
        pa = __builtin_amdgcn_mfma_f32_16x16x32_bf16(af0, WtA[0], pa, 0, 0, 0);
        pa = __builtin_amdgcn_mfma_f32_16x16x32_bf16(af1, WtA[1], pa, 0, 0, 0);
        pb = __builtin_amdgcn_mfma_f32_16x16x32_bf16(af0, WtB[0], pb, 0, 0, 0);
        pb = __builtin_amdgcn_mfma_f32_16x16x32_bf16(af1, WtB[1], pb, 0, 0, 0);
        pc = __builtin_amdgcn_mfma_f32_16x16x32_bf16(af0, WtC[0], pc, 0, 0, 0);
        pc = __builtin_amdgcn_mfma_f32_16x16x32_bf16(af1, WtC[1], pc, 0, 0, 0);
        PA[mt] = pa; PB[mt] = pb; PC[mt] = pc;
    }

    float accN[2][4];
#pragma unroll
    for (int mt = 0; mt < 2; ++mt)
#pragma unroll
        for (int g2 = 0; g2 < 4; ++g2) accN[mt][g2] = 0.f;

    auto process = [&](const ushort_t* SB, float2 a01) {
#pragma unroll
        for (int mt = 0; mt < 2; ++mt) {
            bf16x8 aj0 = *(const bf16x8*)(SB + afo[mt][0]);
            bf16x8 aj1 = *(const bf16x8*)(SB + afo[mt][1]);
            // C-position Sj dwords (rows g2=0..3): ds_read2_b32-formable
            const uint_t* dp = (const uint_t*)(SB + cbo[mt]);
            uint_t d0 = dp[0], d1 = dp[36], d2 = dp[72], d3 = dp[108];
            f32x4 aA = PA[mt], aB = PB[mt], aC = PC[mt];
            aA = __builtin_amdgcn_mfma_f32_16x16x32_bf16(aj0, WbA[0], aA, 0, 0, 0);
            aA = __builtin_amdgcn_mfma_f32_16x16x32_bf16(aj1, WbA[1], aA, 0, 0, 0);
            aB = __builtin_amdgcn_mfma_f32_16x16x32_bf16(aj0, WbB[0], aB, 0, 0, 0);
            aB = __builtin_amdgcn_mfma_f32_16x16x32_bf16(aj1, WbB[1], aB, 0, 0, 0);
            aC = __builtin_amdgcn_mfma_f32_16x16x32_bf16(aj0, WbC[0], aC, 0, 0, 0);
            aC = __builtin_amdgcn_mfma_f32_16x16x32_bf16(aj1, WbC[1], aC, 0, 0, 0);
            float v[4];
            float s = 0.f;
#pragma unroll
            for (int g2 = 0; g2 < 4; ++g2) {
                // frags pre-scaled by log2e -> exp2 direct; leaky commutes
                float x = fmaf(a01.x, aA[g2], fmaf(a01.y, aB[g2], aC[g2]));
                x = fmaxf(x, 0.01f * x);       // leaky_relu
                v[g2] = __builtin_amdgcn_exp2f(x);
                s += v[g2];
            }
            s += __shfl_xor(s, 16);
            const float inv = __builtin_amdgcn_rcpf(s);
            uint_t dd[4] = {d0, d1, d2, d3};
#pragma unroll
            for (int g2 = 0; g2 < 4; ++g2) {
                const float sj = __uint_as_float((dd[g2] << shamt) & 0xFFFF0000u);
                accN[mt][g2] += v[g2] * inv * sj;
            }
        }
    };

    // ---- scalar CSR pipeline, one level deeper than R4 ----
    // entering iter pk: aA/aB_cur = alphas(pair pk); eA1/eB1 = eids(pk+1);
    // eA2/eB2 = eids(pk+2); sa2/sb2 = srcids(pk+2).
    int eA1 = 0, eB1 = 0, eA2 = 0, eB2 = 0, sa2 = 0, sb2 = 0;
    float2 aA_cur = float2{0.f, 0.f}, aB_cur = float2{0.f, 0.f};
    if (deg >= 1) aA_cur = *(const float2*)(alphas + eids[rs] * 2);
    if (deg >= 2) aB_cur = *(const float2*)(alphas + eids[rs + 1] * 2);
    if (deg >= 3) eA1 = eids[rs + 2];
    if (deg >= 4) eB1 = eids[rs + 3];
    if (deg >= 5) { eA2 = eids[rs + 4]; sa2 = srcids[rs + 4]; }
    if (deg >= 6) { eB2 = eids[rs + 5]; sb2 = srcids[rs + 5]; }

    // ---- 2-deep vector prefetch: pfE = pair0, pfO = pair1 ----
    uint2 pfEA[2], pfEB[2], pfOA[2], pfOB[2];
    {
        const ushort_t* pA = out1 + ((deg >= 1) ? srcids[rs]     : 0) * (NB * LSEQ * HDIM);
        const ushort_t* pB = out1 + ((deg >= 2) ? srcids[rs + 1] : 0) * (NB * LSEQ * HDIM);
        const ushort_t* pC = out1 + ((deg >= 3) ? srcids[rs + 2] : 0) * (NB * LSEQ * HDIM);
        const ushort_t* pD = out1 + ((deg >= 4) ? srcids[rs + 3] : 0) * (NB * LSEQ * HDIM);
#pragma unroll
        for (int p = 0; p < 2; ++p) {
            pfEA[p] = *(const uint2*)(pA + glo[p]);
            pfEB[p] = *(const uint2*)(pB + glo[p]);
            pfOA[p] = *(const uint2*)(pC + glo[p]);
            pfOB[p] = *(const uint2*)(pD + glo[p]);
        }
    }

    // ---- self loop (reads slot 0 = Si) ----
    process(Si, aSelf);
    __syncthreads();   // all waves done reading Si before pair 0 overwrites it

    const int npairs = (deg + 1) >> 1;
    for (int pk = 0; pk < npairs; ++pk) {
        const int base = pk * 2;
        ushort_t* SA = sbase + (2 * (pk & 1)) * (32 * SST);
        ushort_t* SB = SA + 32 * SST;

        // write current pair's data, then immediately re-issue the SAME
        // register set with pair pk+2 (2 phases + barrier of load cover).
        if ((pk & 1) == 0) {
#pragma unroll
            for (int p = 0; p < 2; ++p) {
                *(uint2*)(SA + lso[p]) = pfEA[p];
                *(uint2*)(SB + lso[p]) = pfEB[p];
            }
            if (base + 4 < deg) {
                const ushort_t* pA = out1 + sa2 * (NB * LSEQ * HDIM);
#pragma unroll
                for (int p = 0; p < 2; ++p) pfEA[p] = *(const uint2*)(pA + glo[p]);
            }
            if (base + 5 < deg) {
                const ushort_t* pB = out1 + sb2 * (NB * LSEQ * HDIM);
#pragma unroll
                for (int p = 0; p < 2; ++p) pfEB[p] = *(const uint2*)(pB + glo[p]);
            }
        } else {
#pragma unroll
            for (int p = 0; p < 2; ++p) {
                *(uint2*)(SA + lso[p]) = pfOA[p];
                *(uint2*)(SB + lso[p]) = pfOB[p];
            }
            if (base + 4 < deg) {
                const ushort_t* pA = out1 + sa2 * (NB * LSEQ * HDIM);
#pragma unroll
                for (int p = 0; p < 2; ++p) pfOA[p] = *(const uint2*)(pA + glo[p]);
            }
            if (base + 5 < deg) {
                const ushort_t* pB = out1 + sb2 * (NB * LSEQ * HDIM);
#pragma unroll
                for (int p = 0; p < 2; ++p) pfOB[p] = *(const uint2*)(pB + glo[p]);
            }
        }

        // scalar issues for pair pk+3 and alphas for pair pk+1
        int sa_nw = 0, sb_nw = 0, e3A = 0, e3B = 0;
        if (base + 6 < deg) { sa_nw = srcids[rs + base + 6]; e3A = eids[rs + base + 6]; }
        if (base + 7 < deg) { sb_nw = srcids[rs + base + 7]; e3B = eids[rs + base + 7]; }
        float2 aA_n = float2{0.f, 0.f}, aB_n = float2{0.f, 0.f};
        if (base + 2 < deg) aA_n = *(const float2*)(alphas + eA1 * 2);
        if (base + 3 < deg) aB_n = *(const float2*)(alphas + eB1 * 2);

        __syncthreads();   // pair tiles ready (pk-1 slots fully read pre-barrier)

        process(SA, aA_cur);
        if (base + 1 < deg) process(SB, aB_cur);

        // rotate pipelines
        aA_cur = aA_n; aB_cur = aB_n;
        eA1 = eA2; eB1 = eB2; eA2 = e3A; eB2 = e3B;
        sa2 = sa_nw; sb2 = sb_nw;
    }

    // single non-atomic bf16 store of this third-node's aggregate
#pragma unroll
    for (int mt = 0; mt < 2; ++mt)
#pragma unroll
        for (int g2 = 0; g2 < 4; ++g2) {
            const int gr = mh * 32 + mt * 16 + quad * 4 + g2;  // = l*8 + b
            const int b = gr & 7, l = gr >> 3;
            agg[(i * 96 + b * 12 + l) * 64 + n] = fbf(accN[mt][g2]);
        }
}

// ---------------------------------------------------------------------------
// GRU2 (R4 structure + log2e-folded gates): gi AND gh via MFMA; x = relu(agg
// bf16); 16 seqs / 4 waves per block; H+X ping-pong; next x prefetched under
// MFMAs. Weight frags precomputed AND gate-row pre-scaled (mega bx 5501).
// ---------------------------------------------------------------------------
__global__ __launch_bounds__(256) void gru2_kernel(
    const ushort_t* __restrict__ agg, const ushort_t* __restrict__ g2frag,
    const float* __restrict__ bih, const float* __restrict__ bhh,
    float* __restrict__ h2out)
{
    __shared__ ushort_t H[2][16][SST] __attribute__((aligned(16)));
    __shared__ ushort_t X[2][16][SST] __attribute__((aligned(16)));

    const int tid = threadIdx.x;
    const int nw = tid >> 6;
    const int c = tid & 15;
    const int quad = (tid >> 4) & 3;
    const int j = nw * 16 + c;
    const int s0 = blockIdx.x * 16;
    const int sl = tid >> 3, k0 = (tid & 7) * 8;

    if (tid < 128) *(uint4*)&H[0][tid >> 3][(tid & 7) * 8] = uint4{0, 0, 0, 0};

    bf16x8 Bh[3][2], Bi[3][2];
    float bi[3], bh[3];
#pragma unroll
    for (int g = 0; g < 3; ++g) {
        const float sc = (g == 2) ? 2.f * LOG2E : LOG2E;
        const int row = g * 64 + j;
        bi[g] = bih[row] * sc; bh[g] = bhh[row] * sc;
#pragma unroll
        for (int ks = 0; ks < 2; ++ks) {
            Bh[g][ks] = *(const bf16x8*)(g2frag + (((g * 2 + ks) * 2 + 0) * 256 + tid) * 8);
            Bi[g][ks] = *(const bf16x8*)(g2frag + (((g * 2 + ks) * 2 + 1) * 256 + tid) * 8);
        }
    }

    float hold[4];
#pragma unroll
    for (int rg = 0; rg < 4; ++rg) hold[rg] = 0.f;

    if (tid < 128) {
        ushort_t xr[8];
        *(uint4*)xr = *(const uint4*)(agg + (s0 + sl) * (LSEQ * HDIM) + k0);
        ushort_t xs[8];
#pragma unroll
        for (int q = 0; q < 8; ++q) xs[q] = (xr[q] & 0x8000u) ? (ushort_t)0 : xr[q];
        *(uint4*)&X[0][sl][k0] = *(uint4*)xs;
    }

    for (int t = 0; t < LSEQ; ++t) {
        __syncthreads();
        const int rb = t & 1, wb = 1 - rb;
        bf16x8 ah0 = *(const bf16x8*)&H[rb][c][quad * 8];
        bf16x8 ah1 = *(const bf16x8*)&H[rb][c][32 + quad * 8];
        bf16x8 ax0 = *(const bf16x8*)&X[rb][c][quad * 8];
        bf16x8 ax1 = *(const bf16x8*)&X[rb][c][32 + quad * 8];

        ushort_t xr[8];
        if (t < LSEQ - 1 && tid < 128)
            *(uint4*)xr = *(const uint4*)(agg + (s0 + sl) * (LSEQ * HDIM) +
                                          (t + 1) * HDIM + k0);

        f32x4 gh[3], gi[3];
#pragma unroll
        for (int g = 0; g < 3; ++g) {
            f32x4 acc = {0.f, 0.f, 0.f, 0.f};
            acc = __builtin_amdgcn_mfma_f32_16x16x32_bf16(ah0, Bh[g][0], acc, 0, 0, 0);
            acc = __builtin_amdgcn_mfma_f32_16x16x32_bf16(ah1, Bh[g][1], acc, 0, 0, 0);
            gh[g] = acc;
            f32x4 acc2 = {0.f, 0.f, 0.f, 0.f};
            acc2 = __builtin_amdgcn_mfma_f32_16x16x32_bf16(ax0, Bi[g][0], acc2, 0, 0, 0);
            acc2 = __builtin_amdgcn_mfma_f32_16x16x32_bf16(ax1, Bi[g][1], acc2, 0, 0, 0);
            gi[g] = acc2;
        }
#pragma unroll
        for (int rg = 0; rg < 4; ++rg) {
            const int sloc = quad * 4 + rg;
            float r = sigm2(bi[0] + gi[0][rg] + bh[0] + gh[0][rg]);
            float z = sigm2(bi[1] + gi[1][rg] + bh[1] + gh[1][rg]);
            float n = tanh2(bi[2] + gi[2][rg] + r * (bh[2] + gh[2][rg]));
            float hv = (1.f - z) * n + z * hold[rg];
            hold[rg] = hv;
            H[wb][sloc][j] = fbf(hv);
        }
        if (t < LSEQ - 1 && tid < 128) {
            ushort_t xs[8];
#pragma unroll
            for (int q = 0; q < 8; ++q) xs[q] = (xr[q] & 0x8000u) ? (ushort_t)0 : xr[q];
            *(uint4*)&X[wb][sl][k0] = *(uint4*)xs;
        }
    }
#pragma unroll
    for (int rg = 0; rg < 4; ++rg) {
        const int sloc = quad * 4 + rg;
        h2out[(s0 + sloc) * HDIM + j] = hold[rg];
    }
}

extern "C" void kernel_launch(void* const* d_in, const int* in_sizes, int n_in,
                              void* d_out, int out_size, void* d_ws, size_t ws_size,
                              hipStream_t stream)
{
    const float* data     = (const float*)d_in[0];
    const float* features = (const float*)d_in[1];
    const int*   edges    = (const int*)d_in[2];
    const float* Wih1     = (const float*)d_in[3];
    const float* Whh1     = (const float*)d_in[4];
    const float* bih1     = (const float*)d_in[5];
    const float* bhh1     = (const float*)d_in[6];
    const float* W1       = (const float*)d_in[7];
    const float* b1       = (const float*)d_in[8];
    const float* W2       = (const float*)d_in[9];
    const float* b2       = (const float*)d_in[10];
    const float* W3       = (const float*)d_in[11];
    const float* b3       = (const float*)d_in[12];
    const float* Wih2     = (const float*)d_in[13];
    const float* Whh2     = (const float*)d_in[14];
    const float* bih2     = (const float*)d_in[15];
    const float* bhh2     = (const float*)d_in[16];

    float*    out  = (float*)d_out;
    char*     ws   = (char*)d_ws;
    ushort_t* out1 = (ushort_t*)ws;                    // bf16 intermediate
    ushort_t* agg  = (ushort_t*)(ws + OUT1_BYTES);     // bf16 GAT output
    int*      meta = (int*)(ws + OUT1_BYTES + AGG_BYTES);
    int*   degree   = meta;                                 // [2000]
    int*   rowstart = meta + NNODE;                         // [2000]
    int*   srcids   = meta + 2 * NNODE;                     // [16000]
    int*   eids     = meta + 2 * NNODE + NEDGE;             // [16000]
    int*   order    = meta + 2 * NNODE + 2 * NEDGE;         // [2000]
    float* alphas   = (float*)(meta + 3 * NNODE + 2 * NEDGE);  // [36000]
    ushort_t* wfrag  = (ushort_t*)((char*)alphas + 36000 * 4); // [24576] 16B-aligned
    ushort_t* g2frag = wfrag + WFRAG_ELEMS;                    // [24576]

    // 3 dispatches: mega (gru1 || csr || alpha || frag-precompute), gat, gru2.
    mega_kernel<<<1001 + 4500 + 1, 256, 0, stream>>>(
        data, Wih1, Whh1, bih1, bhh1, out1, out,
        edges, degree, rowstart, srcids, eids, order,
        features, W1, b1, W2, b2, alphas,
        W3, b3, Wih2, Whh2, wfrag, g2frag);
    gat_csr_kernel<<<dim3(NNODE, 3), 256, 0, stream>>>(out1, degree, rowstart, srcids,
                                                       eids, order, alphas, wfrag, agg);
    gru2_kernel<<<NSEQ / 16, 256, 0, stream>>>(agg, g2frag, bih2, bhh2,
                                               out + NNODE * NB * HDIM);
}

// Round 7
// 230.658 us; speedup vs baseline: 1.0095x; 1.0001x over previous
//
#include <hip/hip_runtime.h>
#include <hip/hip_bf16.h>

typedef unsigned short ushort_t;
typedef unsigned int uint_t;
typedef __attribute__((ext_vector_type(8))) short bf16x8;
typedef __attribute__((ext_vector_type(4))) float f32x4;

#define NNODE 2000
#define NB 8
#define LSEQ 12
#define HDIM 64
#define NEDGE 16000
#define NSEQ (NNODE * NB)            // 16000 sequences
#define OUT1_ELEMS (NNODE * NB * LSEQ * HDIM)   // 12,288,000
#define OUT1_BYTES (OUT1_ELEMS * 2)             // bf16: 24,576,000
#define AGG_BYTES  (OUT1_ELEMS * 2)             // bf16: 24,576,000
// LDS row stride: multiple of 8 elems (16 B) for ds_read_b128 (R17 lesson).
#define SST 72
#define LOG2E 1.4426950408889634f

// precomputed-fragment table sizes (ushort counts)
#define WFRAG_ELEMS (6 * 2 * 256 * 8)   // gat W3/b3 frags: 24576 (49,152 B)
#define G2FRAG_ELEMS (3 * 2 * 2 * 256 * 8) // gru2 Whh/Wih frags: 24576 (49,152 B)

__device__ __forceinline__ float bf1(ushort_t u) { return __uint_as_float(((uint_t)u) << 16); }
__device__ __forceinline__ ushort_t fbf(float f) {
    uint_t x = __float_as_uint(f);
    uint_t r = x + 0x7fffu + ((x >> 16) & 1u);   // RNE
    return (ushort_t)(r >> 16);
}
// rcp instead of IEEE divide (R2 win): 1 inst vs ~10-inst div sequence.
__device__ __forceinline__ float sigm(float x) {
    return __builtin_amdgcn_rcpf(1.f + __expf(-x));
}
// log2e-folded variants: argument is PRE-SCALED by log2e (sigm2) or
// 2*log2e (tanh2) via the weight/bias tables -- saves the v_mul inside
// every __expf on the serial gate chain (same mechanism as R2's -14.7us).
__device__ __forceinline__ float sigm2(float x) {
    return __builtin_amdgcn_rcpf(1.f + __builtin_amdgcn_exp2f(-x));
}
__device__ __forceinline__ float tanh2(float x) {
    return 2.f * __builtin_amdgcn_rcpf(1.f + __builtin_amdgcn_exp2f(-x)) - 1.f;
}

// ===========================================================================
// MFMA geometry (HW-verified R3): A[m=lane&15][k=quad*8+jj];
// B[k=ks*32+quad*8+jj][n=lane&15]; C row(M)=quad*4+reg, col(N)=lane&15.
// ===========================================================================

// ---------------------------------------------------------------------------
// MEGA kernel (R4 structure):
//   bx 0..999    = GRU1 (log2e-folded gates)
//   bx 1000      = CSR build (int4-vectorized)
//   bx 1001..5500 = alpha MLP (float4 loads)
//   bx 5501      = bf16 fragment precompute (gat wfrag log2e-scaled;
//                  gru2 g2frag gate-row-scaled by log2e / 2log2e)
// ---------------------------------------------------------------------------
__global__ __launch_bounds__(256) void mega_kernel(
    const float* __restrict__ data, const float* __restrict__ Wih,
    const float* __restrict__ Whh, const float* __restrict__ bih,
    const float* __restrict__ bhh, ushort_t* __restrict__ out1,
    float* __restrict__ h1out,
    const int* __restrict__ edges, int* __restrict__ degree,
    int* __restrict__ rowstart, int* __restrict__ srcids,
    int* __restrict__ eids, int* __restrict__ order,
    const float* __restrict__ features,
    const float* __restrict__ W1, const float* __restrict__ b1,
    const float* __restrict__ W2, const float* __restrict__ b2,
    float* __restrict__ alphas,
    const float* __restrict__ W3, const float* __restrict__ b3,
    const float* __restrict__ Wih2, const float* __restrict__ Whh2,
    ushort_t* __restrict__ wfrag, ushort_t* __restrict__ g2frag)
{
    __shared__ ushort_t H[2][16][SST] __attribute__((aligned(16)));
    __shared__ float XD[16][26];
    __shared__ int hist[NNODE];
    __shared__ int wsum[4];
    __shared__ float m1[4][16];
    __shared__ int dh[64];

    const int bx = blockIdx.x;
    const int tid = threadIdx.x;

    if (bx == 5501) {
        // ============ fragment precompute (once per launch) =============
        // gat frags: layout [arr(6)][ks(2)][tid(256)][8 bf16], scaled by log2e
        {
            const int wv = tid >> 6, r = tid & 15, quad = (tid >> 4) & 3;
            const int n = wv * 16 + r;
#pragma unroll
            for (int ks = 0; ks < 2; ++ks) {
                ushort_t ta[8], tb[8], tc[8], ba[8], bb[8], bc[8];
#pragma unroll
                for (int jj = 0; jj < 8; ++jj) {
                    const int mt_ = (ks * 32 + quad * 8 + jj) * 64 + n;
                    float2 w2 = ((const float2*)W3)[mt_];
                    ta[jj] = fbf(w2.x * LOG2E); tb[jj] = fbf(w2.y * LOG2E);
                    tc[jj] = fbf(b3[mt_] * LOG2E);
                    const int mb_ = (64 + ks * 32 + quad * 8 + jj) * 64 + n;
                    float2 w2b = ((const float2*)W3)[mb_];
                    ba[jj] = fbf(w2b.x * LOG2E); bb[jj] = fbf(w2b.y * LOG2E);
                    bc[jj] = fbf(b3[mb_] * LOG2E);
                }
                *(uint4*)(wfrag + ((0 * 2 + ks) * 256 + tid) * 8) = *(uint4*)ta;
                *(uint4*)(wfrag + ((1 * 2 + ks) * 256 + tid) * 8) = *(uint4*)tb;
                *(uint4*)(wfrag + ((2 * 2 + ks) * 256 + tid) * 8) = *(uint4*)tc;
                *(uint4*)(wfrag + ((3 * 2 + ks) * 256 + tid) * 8) = *(uint4*)ba;
                *(uint4*)(wfrag + ((4 * 2 + ks) * 256 + tid) * 8) = *(uint4*)bb;
                *(uint4*)(wfrag + ((5 * 2 + ks) * 256 + tid) * 8) = *(uint4*)bc;
            }
        }
        // gru2 frags: [g(3)][ks(2)][which(2: 0=Bh,1=Bi)][tid(256)][8];
        // gate rows g=0,1 scaled by log2e, g=2 (n-gate) by 2*log2e.
        {
            const int nw = tid >> 6, c = tid & 15, quad = (tid >> 4) & 3;
            const int j = nw * 16 + c;
#pragma unroll
            for (int g = 0; g < 3; ++g) {
                const float sc = (g == 2) ? 2.f * LOG2E : LOG2E;
                const int row = g * 64 + j;
#pragma unroll
                for (int ks = 0; ks < 2; ++ks) {
                    const float* wp = Whh2 + (row << 6) + ks * 32 + quad * 8;
                    float4 wa = *(const float4*)wp;
                    float4 wb = *(const float4*)(wp + 4);
                    ushort_t tmp[8];
                    tmp[0] = fbf(wa.x * sc); tmp[1] = fbf(wa.y * sc);
                    tmp[2] = fbf(wa.z * sc); tmp[3] = fbf(wa.w * sc);
                    tmp[4] = fbf(wb.x * sc); tmp[5] = fbf(wb.y * sc);
                    tmp[6] = fbf(wb.z * sc); tmp[7] = fbf(wb.w * sc);
                    *(uint4*)(g2frag + (((g * 2 + ks) * 2 + 0) * 256 + tid) * 8) = *(uint4*)tmp;
                    const float* wp2 = Wih2 + (row << 6) + ks * 32 + quad * 8;
                    float4 va = *(const float4*)wp2;
                    float4 vb = *(const float4*)(wp2 + 4);
                    tmp[0] = fbf(va.x * sc); tmp[1] = fbf(va.y * sc);
                    tmp[2] = fbf(va.z * sc); tmp[3] = fbf(va.w * sc);
                    tmp[4] = fbf(vb.x * sc); tmp[5] = fbf(vb.y * sc);
                    tmp[6] = fbf(vb.z * sc); tmp[7] = fbf(vb.w * sc);
                    *(uint4*)(g2frag + (((g * 2 + ks) * 2 + 1) * 256 + tid) * 8) = *(uint4*)tmp;
                }
            }
        }
        return;
    }

    if (bx == 1000) {
        // ========== CSR build (single block, int4-vectorized loads) ========
        for (int k = tid; k < NNODE; k += 256) hist[k] = 0;
        if (tid < 64) dh[tid] = 0;
        __syncthreads();
        for (int it = 0; it < 16; ++it) {
            const int e0 = it * 1024 + tid * 4;
            if (e0 + 3 < NEDGE) {
                int4 v4 = *(const int4*)(edges + NEDGE + e0);
                atomicAdd(&hist[v4.x], 1);
                atomicAdd(&hist[v4.y], 1);
                atomicAdd(&hist[v4.z], 1);
                atomicAdd(&hist[v4.w], 1);
            } else {
#pragma unroll
                for (int k = 0; k < 4; ++k) {
                    const int e = e0 + k;
                    if (e < NEDGE) atomicAdd(&hist[edges[NEDGE + e]], 1);
                }
            }
        }
        __syncthreads();
        const int lane = tid & 63, w = tid >> 6;
        int d[8];
        int s = 0;
#pragma unroll
        for (int q = 0; q < 8; ++q) {
            const int idx = tid * 8 + q;
            d[q] = (idx < NNODE) ? hist[idx] : 0;
            s += d[q];
        }
        int v = s;
#pragma unroll
        for (int off = 1; off < 64; off <<= 1) {
            int u = __shfl_up(v, off);
            if (lane >= off) v += u;
        }
        if (lane == 63) wsum[w] = v;
        __syncthreads();
        int base = 0;
        for (int k = 0; k < 4; ++k) if (k < w) base += wsum[k];
        int run = base + v - s;
        int rs8[8];
#pragma unroll
        for (int q = 0; q < 8; ++q) {
            const int idx = tid * 8 + q;
            if (idx < NNODE) {
                rs8[q] = run;
                rowstart[idx] = run;
                degree[idx] = d[q];
                run += d[q];
                atomicAdd(&dh[63 - min(d[q], 63)], 1);   // descending-degree key
            }
        }
        __syncthreads();
        if (tid == 0) {          // serial prefix over 64 buckets
            int acc = 0;
            for (int k = 0; k < 64; ++k) { const int c = dh[k]; dh[k] = acc; acc += c; }
        }
        __syncthreads();
        // scatter nodes into order[] (longest first)
#pragma unroll
        for (int q = 0; q < 8; ++q) {
            const int idx = tid * 8 + q;
            if (idx < NNODE) {
                const int pos = atomicAdd(&dh[63 - min(d[q], 63)], 1);
                order[pos] = idx;
            }
        }
        // reuse hist as scatter cursor
        __syncthreads();
#pragma unroll
        for (int q = 0; q < 8; ++q) {
            const int idx = tid * 8 + q;
            if (idx < NNODE) hist[idx] = rs8[q];
        }
        __syncthreads();
        for (int it = 0; it < 16; ++it) {
            const int e0 = it * 1024 + tid * 4;
            if (e0 + 3 < NEDGE) {
                int4 dv4 = *(const int4*)(edges + NEDGE + e0);
                int4 sv4 = *(const int4*)(edges + e0);
                int pos;
                pos = atomicAdd(&hist[dv4.x], 1); srcids[pos] = sv4.x; eids[pos] = e0;
                pos = atomicAdd(&hist[dv4.y], 1); srcids[pos] = sv4.y; eids[pos] = e0 + 1;
                pos = atomicAdd(&hist[dv4.z], 1); srcids[pos] = sv4.z; eids[pos] = e0 + 2;
                pos = atomicAdd(&hist[dv4.w], 1); srcids[pos] = sv4.w; eids[pos] = e0 + 3;
            } else {
#pragma unroll
                for (int k = 0; k < 4; ++k) {
                    const int e = e0 + k;
                    if (e < NEDGE) {
                        const int pos = atomicAdd(&hist[edges[NEDGE + e]], 1);
                        srcids[pos] = edges[e];
                        eids[pos] = e;
                    }
                }
            }
        }
        return;
    }

    if (bx > 1000) {
        // ============ alpha MLP (4 edges/block, float4 loads) ============
        const int w = tid >> 6, lane = tid & 63;
        const int e = (bx - 1001) * 4 + w;
        int i, j;
        if (e < NEDGE) { j = edges[e]; i = edges[NEDGE + e]; }
        else { i = j = e - NEDGE; }
        const int o = lane >> 2, q = lane & 3;
        const float* fsrc = (q < 2) ? (features + i * 64 + q * 32)
                                    : (features + j * 64 + (q - 2) * 32);
        const float* wsrc = W1 + o * 128 + q * 32;
        const float4* f4 = (const float4*)fsrc;
        const float4* w4 = (const float4*)wsrc;
        float acc = 0.f;
#pragma unroll
        for (int k = 0; k < 8; ++k) {
            float4 a = f4[k], b = w4[k];
            acc = fmaf(a.x, b.x, acc);
            acc = fmaf(a.y, b.y, acc);
            acc = fmaf(a.z, b.z, acc);
            acc = fmaf(a.w, b.w, acc);
        }
        acc += __shfl_xor(acc, 1);
        acc += __shfl_xor(acc, 2);
        if (q == 0) m1[w][o] = sigm(acc + b1[o]);
        __syncthreads();
        if (lane < 32 && e < NEDGE + NNODE) {
            const int o2 = lane >> 4, k = lane & 15;
            float p = m1[w][k] * W2[o2 * 16 + k];
            p += __shfl_xor(p, 1);
            p += __shfl_xor(p, 2);
            p += __shfl_xor(p, 4);
            p += __shfl_xor(p, 8);
            if (k == 0) alphas[e * 2 + o2] = sigm(p + b2[o2]);
        }
        return;
    }

    // ================= GRU1 (blocks 0..999), log2e-folded gates ==========
    const int nw = tid >> 6;
    const int c = tid & 15;
    const int quad = (tid >> 4) & 3;
    const int j = nw * 16 + c;
    const int s0 = bx * 16;
    const int crow = tid >> 4, ccol = (tid & 15) * 4;   // out1 copy mapping (uint2)

    if (tid < 128) *(uint4*)&H[0][tid >> 3][(tid & 7) * 8] = uint4{0, 0, 0, 0};
#pragma unroll
    for (int p = 0; p < 2; ++p) {
        const int flat = p * 256 + tid;
        if (flat < 384) {
            const int sl = flat / 24, q = flat - sl * 24;
            XD[sl][q] = data[(s0 + sl) * 24 + q];
        }
    }

    bf16x8 Bh[3][2];
    float wi0[3], wi1[3], bi[3], bh[3];
#pragma unroll
    for (int g = 0; g < 3; ++g) {
        const float sc = (g == 2) ? 2.f * LOG2E : LOG2E;   // gate pre-scaling
        const int row = g * 64 + j;
        float2 wi = *(const float2*)(Wih + row * 2);
        wi0[g] = wi.x * sc; wi1[g] = wi.y * sc;
        bi[g] = bih[row] * sc; bh[g] = bhh[row] * sc;
#pragma unroll
        for (int ks = 0; ks < 2; ++ks) {
            const float* wp = Whh + (row << 6) + ks * 32 + quad * 8;
            float4 wa = *(const float4*)wp;
            float4 wb = *(const float4*)(wp + 4);
            ushort_t tmp[8];
            tmp[0] = fbf(wa.x * sc); tmp[1] = fbf(wa.y * sc);
            tmp[2] = fbf(wa.z * sc); tmp[3] = fbf(wa.w * sc);
            tmp[4] = fbf(wb.x * sc); tmp[5] = fbf(wb.y * sc);
            tmp[6] = fbf(wb.z * sc); tmp[7] = fbf(wb.w * sc);
            Bh[g][ks] = *(bf16x8*)tmp;
        }
    }

    float hold[4];
#pragma unroll
    for (int rg = 0; rg < 4; ++rg) hold[rg] = 0.f;

    for (int t = 0; t < LSEQ; ++t) {
        __syncthreads();
        const ushort_t (*Hr)[SST] = H[t & 1];
        ushort_t (*Hw)[SST] = H[1 - (t & 1)];
        bf16x8 a0 = *(const bf16x8*)&Hr[c][quad * 8];
        bf16x8 a1 = *(const bf16x8*)&Hr[c][32 + quad * 8];
        // coalesced out1 write of h_{t-1} from the stable read buffer
        if (t > 0)
            *(uint2*)(out1 + (s0 + crow) * (LSEQ * HDIM) + (t - 1) * HDIM + ccol) =
                *(const uint2*)&Hr[crow][ccol];
        f32x4 gh[3];
#pragma unroll
        for (int g = 0; g < 3; ++g) {
            f32x4 acc = {0.f, 0.f, 0.f, 0.f};
            acc = __builtin_amdgcn_mfma_f32_16x16x32_bf16(a0, Bh[g][0], acc, 0, 0, 0);
            acc = __builtin_amdgcn_mfma_f32_16x16x32_bf16(a1, Bh[g][1], acc, 0, 0, 0);
            gh[g] = acc;
        }
#pragma unroll
        for (int rg = 0; rg < 4; ++rg) {
            const int sloc = quad * 4 + rg;
            float2 xp = *(const float2*)&XD[sloc][2 * t];
            float gr = bh[0] + gh[0][rg];
            float gz = bh[1] + gh[1][rg];
            float gn = bh[2] + gh[2][rg];
            float ir = bi[0] + wi0[0] * xp.x + wi1[0] * xp.y;
            float iz = bi[1] + wi0[1] * xp.x + wi1[1] * xp.y;
            float in = bi[2] + wi0[2] * xp.x + wi1[2] * xp.y;
            float r = sigm2(ir + gr);          // args pre-scaled by log2e
            float z = sigm2(iz + gz);
            float n = tanh2(in + r * gn);      // pre-scaled by 2*log2e
            float hv = (1.f - z) * n + z * hold[rg];
            hold[rg] = hv;
            Hw[sloc][j] = fbf(hv);
        }
    }
    __syncthreads();   // final H[LSEQ&1] (= h_{11}) complete
    *(uint2*)(out1 + (s0 + crow) * (LSEQ * HDIM) + (LSEQ - 1) * HDIM + ccol) =
        *(const uint2*)&H[LSEQ & 1][crow][ccol];
#pragma unroll
    for (int rg = 0; rg < 4; ++rg) {
        const int sloc = quad * 4 + rg;
        h1out[(s0 + sloc) * HDIM + j] = hold[rg];
    }
}

// ---------------------------------------------------------------------------
// MetaGAT (R7): QUAD-batched edge loop -- 8 LDS slots (36.9 KB), 4 edges
// staged per barrier instead of 2. Halves the per-edge barrier+vmcnt-drain
// overhead (~25% of phase time at R4's 2-edge batching) and gives each tile
// load ~4 process calls of latency cover. Load placement follows the PROVEN
// R4 discipline: vector loads issued AFTER the barrier (R6 lesson: loads
// issued before s_barrier are drained by the compiler's vmcnt(0) with zero
// cover). Scalar CSR metadata pipelined 2 quads deep.
// ---------------------------------------------------------------------------
__global__ __launch_bounds__(256) void gat_csr_kernel(
    const ushort_t* __restrict__ out1,
    const int* __restrict__ degree, const int* __restrict__ rowstart,
    const int* __restrict__ srcids, const int* __restrict__ eids,
    const int* __restrict__ order,
    const float* __restrict__ alphas,
    const ushort_t* __restrict__ wfrag,
    ushort_t* __restrict__ agg)
{
    __shared__ ushort_t POOL[8][32][SST] __attribute__((aligned(16)));  // 36864 B

    const int tid = threadIdx.x;
    const int i = order[blockIdx.x];      // degree-descending schedule
    const int mh = blockIdx.y;            // M-third
    const int deg = degree[i];
    const int rs = rowstart[i];

    const int wv = tid >> 6;              // N-strip
    const int r = tid & 15;
    const int quad = (tid >> 4) & 3;
    const int n = wv * 16 + r;

    // self-loop alpha: issue early (uniform s_load, consumed after preamble)
    const float2 aSelf = *(const float2*)(alphas + (NEDGE + i) * 2);

    // ---- precomputed invariant offsets ----
    int glo[2], lso[2];
#pragma unroll
    for (int p = 0; p < 2; ++p) {
        const int u = p * 256 + tid;
        const int rr = u >> 4, c4 = u & 15;
        const int b = rr & 7, l = (rr >> 3) + 4 * mh;
        glo[p] = (b * 12 + l) * 64 + c4 * 4;
        lso[p] = rr * SST + c4 * 4;
    }
    int afo[2][2];
#pragma unroll
    for (int mt = 0; mt < 2; ++mt) {
        afo[mt][0] = (mt * 16 + r) * SST + quad * 8;
        afo[mt][1] = afo[mt][0] + 32;
    }
    // C-position dword base offsets (ushort units, even): rows quad*4+g2,
    // col pair n&~1. g2 strides are +SST ushorts = +36 dwords.
    int cbo[2];
#pragma unroll
    for (int mt = 0; mt < 2; ++mt)
        cbo[mt] = (mt * 16 + quad * 4) * SST + (n & ~1);
    const uint_t shamt = (n & 1) ? 0u : 16u;   // bf16 in hi/lo half of dword

    const ushort_t* pi = out1 + i * (NB * LSEQ * HDIM);
    ushort_t* const sbase = &POOL[0][0][0];
    ushort_t* const Si = sbase;           // slot 0 doubles as Si

    // ---- stage Si (slot 0) ----
#pragma unroll
    for (int p = 0; p < 2; ++p)
        *(uint2*)(Si + lso[p]) = *(const uint2*)(pi + glo[p]);

    // ---- fixed B-frags: 12 coalesced dwordx4 loads from precompute table ----
    bf16x8 WtA[2], WtB[2], WtC[2], WbA[2], WbB[2], WbC[2];
#pragma unroll
    for (int ks = 0; ks < 2; ++ks) {
        WtA[ks] = *(const bf16x8*)(wfrag + ((0 * 2 + ks) * 256 + tid) * 8);
        WtB[ks] = *(const bf16x8*)(wfrag + ((1 * 2 + ks) * 256 + tid) * 8);
        WtC[ks] = *(const bf16x8*)(wfrag + ((2 * 2 + ks) * 256 + tid) * 8);
        WbA[ks] = *(const bf16x8*)(wfrag + ((3 * 2 + ks) * 256 + tid) * 8);
        WbB[ks] = *(const bf16x8*)(wfrag + ((4 * 2 + ks) * 256 + tid) * 8);
        WbC[ks] = *(const bf16x8*)(wfrag + ((5 * 2 + ks) * 256 + tid) * 8);
    }

    // ---- scalar CSR pipeline init: alphas(quad 0), ids(quad 1) ----
    float2 aC[4];
    int e1[4], s1[4];
#pragma unroll
    for (int k = 0; k < 4; ++k) {
        aC[k] = float2{0.f, 0.f};
        if (k < deg) aC[k] = *(const float2*)(alphas + eids[rs + k] * 2);
        const int idx = 4 + k;
        e1[k] = 0; s1[k] = 0;
        if (idx < deg) { e1[k] = eids[rs + idx]; s1[k] = srcids[rs + idx]; }
    }

    // ---- vector prefetch quad 0 (edges 0..3) ----
    uint2 pf[4][2];
#pragma unroll
    for (int k = 0; k < 4; ++k) {
        const ushort_t* pA = out1 + ((k < deg) ? srcids[rs + k] : 0) * (NB * LSEQ * HDIM);
#pragma unroll
        for (int p = 0; p < 2; ++p) pf[k][p] = *(const uint2*)(pA + glo[p]);
    }

    __syncthreads();   // Si ready

    // ---- preamble: Si-projections PA/PB/PC ----
    f32x4 PA[2], PB[2], PC[2];
#pragma unroll
    for (int mt = 0; mt < 2; ++mt) {
        bf16x8 af0 = *(const bf16x8*)(Si + afo[mt][0]);
        bf16x8 af1 = *(const bf16x8*)(Si + afo[mt][1]);
        f32x4 pa = {0.f, 0.f, 0.f, 0.f};
        f32x4 pb = {0.f, 0.f, 0.f, 0.f};
        f32x4 pc = {0.f, 0.f, 0.f, 0.f};
        pa = __builtin_amdgcn_mfma_f32_16x16x32_bf16(af0, WtA[0], pa, 0, 0, 0);
        pa = __builtin_amdgcn_mfma_f32_16x16x32_bf16(af1, WtA[1], pa, 0, 0, 0);
        pb = __builtin_amdgcn_mfma_f32_16x16x32_bf16(af0, WtB[0], pb, 0, 0, 0);
        pb = __builtin_amdgcn_mfma_f32_16x16x32_bf16(af1, WtB[1], pb, 0, 0, 0);
        pc = __builtin_amdgcn_mfma_f32_16x16x32_bf16(af0, WtC[0], pc, 0, 0, 0);
        pc = __builtin_amdgcn_mfma_f32_16x16x32_bf16(af1, WtC[1], pc, 0, 0, 0);
        PA[mt] = pa; PB[mt] = pb; PC[mt] = pc;
    }

    float accN[2][4];
#pragma unroll
    for (int mt = 0; mt < 2; ++mt)
#pragma unroll
        for (int g2 = 0; g2 < 4; ++g2) accN[mt][g2] = 0.f;

    auto process = [&](const ushort_t* SB, float2 a01) {
#pragma unroll
        for (int mt = 0; mt < 2; ++mt) {
            bf16x8 aj0 = *(const bf16x8*)(SB + afo[mt][0]);
            bf16x8 aj1 = *(const bf16x8*)(SB + afo[mt][1]);
            // C-position Sj dwords (rows g2=0..3): ds_read2_b32-formable
            const uint_t* dp = (const uint_t*)(SB + cbo[mt]);
            uint_t d0 = dp[0], d1 = dp[36], d2 = dp[72], d3 = dp[108];
            f32x4 aA = PA[mt], aB = PB[mt], aC_ = PC[mt];
            aA = __builtin_amdgcn_mfma_f32_16x16x32_bf16(aj0, WbA[0], aA, 0, 0, 0);
            aA = __builtin_amdgcn_mfma_f32_16x16x32_bf16(aj1, WbA[1], aA, 0, 0, 0);
            aB = __builtin_amdgcn_mfma_f32_16x16x32_bf16(aj0, WbB[0], aB, 0, 0, 0);
            aB = __builtin_amdgcn_mfma_f32_16x16x32_bf16(aj1, WbB[1], aB, 0, 0, 0);
            aC_ = __builtin_amdgcn_mfma_f32_16x16x32_bf16(aj0, WbC[0], aC_, 0, 0, 0);
            aC_ = __builtin_amdgcn_mfma_f32_16x16x32_bf16(aj1, WbC[1], aC_, 0, 0, 0);
            float v[4];
            float s = 0.f;
#pragma unroll
            for (int g2 = 0; g2 < 4; ++g2) {
                // frags pre-scaled by log2e -> exp2 direct; leaky commutes
                float x = fmaf(a01.x, aA[g2], fmaf(a01.y, aB[g2], aC_[g2]));
                x = fmaxf(x, 0.01f * x);       // leaky_relu
                v[g2] = __builtin_amdgcn_exp2f(x);
                s += v[g2];
            }
            s += __shfl_xor(s, 16);
            const float inv = __builtin_amdgcn_rcpf(s);
            uint_t dd[4] = {d0, d1, d2, d3};
#pragma unroll
            for (int g2 = 0; g2 < 4; ++g2) {
                const float sj = __uint_as_float((dd[g2] << shamt) & 0xFFFF0000u);
                accN[mt][g2] += v[g2] * inv * sj;
            }
        }
    };

    // ---- self loop (reads slot 0 = Si) ----
    process(Si, aSelf);
    __syncthreads();   // all waves done reading Si before quad 0 overwrites it

    const int nquads = (deg + 3) >> 2;
    for (int qk = 0; qk < nquads; ++qk) {
        const int base = qk * 4;
        ushort_t* S0 = sbase + ((qk & 1) * 4) * (32 * SST);

        // write current quad's tiles (pf loaded last iteration / init)
#pragma unroll
        for (int k = 0; k < 4; ++k) {
            if (base + k < deg) {
                ushort_t* Sk = S0 + k * (32 * SST);
#pragma unroll
                for (int p = 0; p < 2; ++p) *(uint2*)(Sk + lso[p]) = pf[k][p];
            }
        }

        // scalar: alphas for quad qk+1 (via e1 loaded last iter -> no chain),
        // ids for quad qk+2
        float2 aN[4];
        int e2[4], s2[4];
#pragma unroll
        for (int k = 0; k < 4; ++k) {
            aN[k] = float2{0.f, 0.f};
            if (base + 4 + k < deg) aN[k] = *(const float2*)(alphas + e1[k] * 2);
            const int idx = base + 8 + k;
            e2[k] = 0; s2[k] = 0;
            if (idx < deg) { e2[k] = eids[rs + idx]; s2[k] = srcids[rs + idx]; }
        }

        __syncthreads();   // quad tiles ready; NO vector loads in flight here

        // vector loads for quad qk+1 (addresses s1 from last iter) -- issued
        // AFTER the barrier so they get the full 4-process phase of cover
#pragma unroll
        for (int k = 0; k < 4; ++k) {
            if (base + 4 + k < deg) {
                const ushort_t* pA = out1 + s1[k] * (NB * LSEQ * HDIM);
#pragma unroll
                for (int p = 0; p < 2; ++p) pf[k][p] = *(const uint2*)(pA + glo[p]);
            }
        }

        // process 4 edges
#pragma unroll
        for (int k = 0; k < 4; ++k) {
            if (base + k < deg) process(S0 + k * (32 * SST), aC[k]);
        }

        // rotate pipelines
#pragma unroll
        for (int k = 0; k < 4; ++k) { aC[k] = aN[k]; e1[k] = e2[k]; s1[k] = s2[k]; }
    }

    // single non-atomic bf16 store of this third-node's aggregate
#pragma unroll
    for (int mt = 0; mt < 2; ++mt)
#pragma unroll
        for (int g2 = 0; g2 < 4; ++g2) {
            const int gr = mh * 32 + mt * 16 + quad * 4 + g2;  // = l*8 + b
            const int b = gr & 7, l = gr >> 3;
            agg[(i * 96 + b * 12 + l) * 64 + n] = fbf(accN[mt][g2]);
        }
}

// ---------------------------------------------------------------------------
// GRU2 (R4 structure + log2e-folded gates): gi AND gh via MFMA; x = relu(agg
// bf16); 16 seqs / 4 waves per block; H+X ping-pong; next x prefetched under
// MFMAs. Weight frags precomputed AND gate-row pre-scaled (mega bx 5501).
// ---------------------------------------------------------------------------
__global__ __launch_bounds__(256) void gru2_kernel(
    const ushort_t* __restrict__ agg, const ushort_t* __restrict__ g2frag,
    const float* __restrict__ bih, const float* __restrict__ bhh,
    float* __restrict__ h2out)
{
    __shared__ ushort_t H[2][16][SST] __attribute__((aligned(16)));
    __shared__ ushort_t X[2][16][SST] __attribute__((aligned(16)));

    const int tid = threadIdx.x;
    const int nw = tid >> 6;
    const int c = tid & 15;
    const int quad = (tid >> 4) & 3;
    const int j = nw * 16 + c;
    const int s0 = blockIdx.x * 16;
    const int sl = tid >> 3, k0 = (tid & 7) * 8;

    if (tid < 128) *(uint4*)&H[0][tid >> 3][(tid & 7) * 8] = uint4{0, 0, 0, 0};

    bf16x8 Bh[3][2], Bi[3][2];
    float bi[3], bh[3];
#pragma unroll
    for (int g = 0; g < 3; ++g) {
        const float sc = (g == 2) ? 2.f * LOG2E : LOG2E;
        const int row = g * 64 + j;
        bi[g] = bih[row] * sc; bh[g] = bhh[row] * sc;
#pragma unroll
        for (int ks = 0; ks < 2; ++ks) {
            Bh[g][ks] = *(const bf16x8*)(g2frag + (((g * 2 + ks) * 2 + 0) * 256 + tid) * 8);
            Bi[g][ks] = *(const bf16x8*)(g2frag + (((g * 2 + ks) * 2 + 1) * 256 + tid) * 8);
        }
    }

    float hold[4];
#pragma unroll
    for (int rg = 0; rg < 4; ++rg) hold[rg] = 0.f;

    if (tid < 128) {
        ushort_t xr[8];
        *(uint4*)xr = *(const uint4*)(agg + (s0 + sl) * (LSEQ * HDIM) + k0);
        ushort_t xs[8];
#pragma unroll
        for (int q = 0; q < 8; ++q) xs[q] = (xr[q] & 0x8000u) ? (ushort_t)0 : xr[q];
        *(uint4*)&X[0][sl][k0] = *(uint4*)xs;
    }

    for (int t = 0; t < LSEQ; ++t) {
        __syncthreads();
        const int rb = t & 1, wb = 1 - rb;
        bf16x8 ah0 = *(const bf16x8*)&H[rb][c][quad * 8];
        bf16x8 ah1 = *(const bf16x8*)&H[rb][c][32 + quad * 8];
        bf16x8 ax0 = *(const bf16x8*)&X[rb][c][quad * 8];
        bf16x8 ax1 = *(const bf16x8*)&X[rb][c][32 + quad * 8];

        ushort_t xr[8];
        if (t < LSEQ - 1 && tid < 128)
            *(uint4*)xr = *(const uint4*)(agg + (s0 + sl) * (LSEQ * HDIM) +
                                          (t + 1) * HDIM + k0);

        f32x4 gh[3], gi[3];
#pragma unroll
        for (int g = 0; g < 3; ++g) {
            f32x4 acc = {0.f, 0.f, 0.f, 0.f};
            acc = __builtin_amdgcn_mfma_f32_16x16x32_bf16(ah0, Bh[g][0], acc, 0, 0, 0);
            acc = __builtin_amdgcn_mfma_f32_16x16x32_bf16(ah1, Bh[g][1], acc, 0, 0, 0);
            gh[g] = acc;
            f32x4 acc2 = {0.f, 0.f, 0.f, 0.f};
            acc2 = __builtin_amdgcn_mfma_f32_16x16x32_bf16(ax0, Bi[g][0], acc2, 0, 0, 0);
            acc2 = __builtin_amdgcn_mfma_f32_16x16x32_bf16(ax1, Bi[g][1], acc2, 0, 0, 0);
            gi[g] = acc2;
        }
#pragma unroll
        for (int rg = 0; rg < 4; ++rg) {
            const int sloc = quad * 4 + rg;
            float r = sigm2(bi[0] + gi[0][rg] + bh[0] + gh[0][rg]);
            float z = sigm2(bi[1] + gi[1][rg] + bh[1] + gh[1][rg]);
            float n = tanh2(bi[2] + gi[2][rg] + r * (bh[2] + gh[2][rg]));
            float hv = (1.f - z) * n + z * hold[rg];
            hold[rg] = hv;
            H[wb][sloc][j] = fbf(hv);
        }
        if (t < LSEQ - 1 && tid < 128) {
            ushort_t xs[8];
#pragma unroll
            for (int q = 0; q < 8; ++q) xs[q] = (xr[q] & 0x8000u) ? (ushort_t)0 : xr[q];
            *(uint4*)&X[wb][sl][k0] = *(uint4*)xs;
        }
    }
#pragma unroll
    for (int rg = 0; rg < 4; ++rg) {
        const int sloc = quad * 4 + rg;
        h2out[(s0 + sloc) * HDIM + j] = hold[rg];
    }
}

extern "C" void kernel_launch(void* const* d_in, const int* in_sizes, int n_in,
                              void* d_out, int out_size, void* d_ws, size_t ws_size,
                              hipStream_t stream)
{
    const float* data     = (const float*)d_in[0];
    const float* features = (const float*)d_in[1];
    const int*   edges    = (const int*)d_in[2];
    const float* Wih1     = (const float*)d_in[3];
    const float* Whh1     = (const float*)d_in[4];
    const float* bih1     = (const float*)d_in[5];
    const float* bhh1     = (const float*)d_in[6];
    const float* W1       = (const float*)d_in[7];
    const float* b1       = (const float*)d_in[8];
    const float* W2       = (const float*)d_in[9];
    const float* b2       = (const float*)d_in[10];
    const float* W3       = (const float*)d_in[11];
    const float* b3       = (const float*)d_in[12];
    const float* Wih2     = (const float*)d_in[13];
    const float* Whh2     = (const float*)d_in[14];
    const float* bih2     = (const float*)d_in[15];
    const float* bhh2     = (const float*)d_in[16];

    float*    out  = (float*)d_out;
    char*     ws   = (char*)d_ws;
    ushort_t* out1 = (ushort_t*)ws;                    // bf16 intermediate
    ushort_t* agg  = (ushort_t*)(ws + OUT1_BYTES);     // bf16 GAT output
    int*      meta = (int*)(ws + OUT1_BYTES + AGG_BYTES);
    int*   degree   = meta;                                 // [2000]
    int*   rowstart = meta + NNODE;                         // [2000]
    int*   srcids   = meta + 2 * NNODE;                     // [16000]
    int*   eids     = meta + 2 * NNODE + NEDGE;             // [16000]
    int*   order    = meta + 2 * NNODE + 2 * NEDGE;         // [2000]
    float* alphas   = (float*)(meta + 3 * NNODE + 2 * NEDGE);  // [36000]
    ushort_t* wfrag  = (ushort_t*)((char*)alphas + 36000 * 4); // [24576] 16B-aligned
    ushort_t* g2frag = wfrag + WFRAG_ELEMS;                    // [24576]

    // 3 dispatches: mega (gru1 || csr || alpha || frag-precompute), gat, gru2.
    mega_kernel<<<1001 + 4500 + 1, 256, 0, stream>>>(
        data, Wih1, Whh1, bih1, bhh1, out1, out,
        edges, degree, rowstart, srcids, eids, order,
        features, W1, b1, W2, b2, alphas,
        W3, b3, Wih2, Whh2, wfrag, g2frag);
    gat_csr_kernel<<<dim3(NNODE, 3), 256, 0, stream>>>(out1, degree, rowstart, srcids,
                                                       eids, order, alphas, wfrag, agg);
    gru2_kernel<<<NSEQ / 16, 256, 0, stream>>>(agg, g2frag, bih2, bhh2,
                                               out + NNODE * NB * HDIM);
}

// Round 8
// 226.379 us; speedup vs baseline: 1.0285x; 1.0189x over previous
//
#include <hip/hip_runtime.h>
#include <hip/hip_bf16.h>

typedef unsigned short ushort_t;
typedef unsigned int uint_t;
typedef __attribute__((ext_vector_type(8))) short bf16x8;
typedef __attribute__((ext_vector_type(4))) float f32x4;

#define NNODE 2000
#define NB 8
#define LSEQ 12
#define HDIM 64
#define NEDGE 16000
#define NSEQ (NNODE * NB)            // 16000 sequences
#define OUT1_ELEMS (NNODE * NB * LSEQ * HDIM)   // 12,288,000
#define OUT1_BYTES (OUT1_ELEMS * 2)             // bf16: 24,576,000
#define AGG_BYTES  (OUT1_ELEMS * 2)             // bf16: 24,576,000
// LDS row stride: multiple of 8 elems (16 B) for ds_read_b128 (R17 lesson).
#define SST 72
#define LOG2E 1.4426950408889634f

// precomputed-fragment table sizes (ushort counts)
#define WFRAG_ELEMS (6 * 2 * 256 * 8)   // gat W3/b3 frags: 24576 (49,152 B)
#define G2FRAG_ELEMS (3 * 2 * 2 * 256 * 8) // gru2 Whh/Wih frags: 24576 (49,152 B)

__device__ __forceinline__ float bf1(ushort_t u) { return __uint_as_float(((uint_t)u) << 16); }
__device__ __forceinline__ ushort_t fbf(float f) {
    uint_t x = __float_as_uint(f);
    uint_t r = x + 0x7fffu + ((x >> 16) & 1u);   // RNE
    return (ushort_t)(r >> 16);
}
// rcp instead of IEEE divide (R2 win): 1 inst vs ~10-inst div sequence.
__device__ __forceinline__ float sigm(float x) {
    return __builtin_amdgcn_rcpf(1.f + __expf(-x));
}
// log2e-folded variants: argument is PRE-SCALED by log2e (sigm2) or
// 2*log2e (tanh2) via the weight/bias tables -- saves the v_mul inside
// every __expf on the serial gate chain (same mechanism as R2's -14.7us).
__device__ __forceinline__ float sigm2(float x) {
    return __builtin_amdgcn_rcpf(1.f + __builtin_amdgcn_exp2f(-x));
}
__device__ __forceinline__ float tanh2(float x) {
    return 2.f * __builtin_amdgcn_rcpf(1.f + __builtin_amdgcn_exp2f(-x)) - 1.f;
}

// ===========================================================================
// MFMA geometry (HW-verified R3): A[m=lane&15][k=quad*8+jj];
// B[k=ks*32+quad*8+jj][n=lane&15]; C row(M)=quad*4+reg, col(N)=lane&15.
// ===========================================================================

// ---------------------------------------------------------------------------
// MEGA kernel (R4 structure):
//   bx 0..999    = GRU1 (log2e-folded gates)
//   bx 1000      = CSR build (int4-vectorized)
//   bx 1001..5500 = alpha MLP (float4 loads)
//   bx 5501      = bf16 fragment precompute (gat wfrag log2e-scaled;
//                  gru2 g2frag gate-row-scaled by log2e / 2log2e)
// ---------------------------------------------------------------------------
__global__ __launch_bounds__(256) void mega_kernel(
    const float* __restrict__ data, const float* __restrict__ Wih,
    const float* __restrict__ Whh, const float* __restrict__ bih,
    const float* __restrict__ bhh, ushort_t* __restrict__ out1,
    float* __restrict__ h1out,
    const int* __restrict__ edges, int* __restrict__ degree,
    int* __restrict__ rowstart, int* __restrict__ srcids,
    int* __restrict__ eids, int* __restrict__ order,
    const float* __restrict__ features,
    const float* __restrict__ W1, const float* __restrict__ b1,
    const float* __restrict__ W2, const float* __restrict__ b2,
    float* __restrict__ alphas,
    const float* __restrict__ W3, const float* __restrict__ b3,
    const float* __restrict__ Wih2, const float* __restrict__ Whh2,
    ushort_t* __restrict__ wfrag, ushort_t* __restrict__ g2frag)
{
    __shared__ ushort_t H[2][16][SST] __attribute__((aligned(16)));
    __shared__ float XD[16][26];
    __shared__ int hist[NNODE];
    __shared__ int wsum[4];
    __shared__ float m1[4][16];
    __shared__ int dh[64];

    const int bx = blockIdx.x;
    const int tid = threadIdx.x;

    if (bx == 5501) {
        // ============ fragment precompute (once per launch) =============
        // gat frags: layout [arr(6)][ks(2)][tid(256)][8 bf16], scaled by log2e
        {
            const int wv = tid >> 6, r = tid & 15, quad = (tid >> 4) & 3;
            const int n = wv * 16 + r;
#pragma unroll
            for (int ks = 0; ks < 2; ++ks) {
                ushort_t ta[8], tb[8], tc[8], ba[8], bb[8], bc[8];
#pragma unroll
                for (int jj = 0; jj < 8; ++jj) {
                    const int mt_ = (ks * 32 + quad * 8 + jj) * 64 + n;
                    float2 w2 = ((const float2*)W3)[mt_];
                    ta[jj] = fbf(w2.x * LOG2E); tb[jj] = fbf(w2.y * LOG2E);
                    tc[jj] = fbf(b3[mt_] * LOG2E);
                    const int mb_ = (64 + ks * 32 + quad * 8 + jj) * 64 + n;
                    float2 w2b = ((const float2*)W3)[mb_];
                    ba[jj] = fbf(w2b.x * LOG2E); bb[jj] = fbf(w2b.y * LOG2E);
                    bc[jj] = fbf(b3[mb_] * LOG2E);
                }
                *(uint4*)(wfrag + ((0 * 2 + ks) * 256 + tid) * 8) = *(uint4*)ta;
                *(uint4*)(wfrag + ((1 * 2 + ks) * 256 + tid) * 8) = *(uint4*)tb;
                *(uint4*)(wfrag + ((2 * 2 + ks) * 256 + tid) * 8) = *(uint4*)tc;
                *(uint4*)(wfrag + ((3 * 2 + ks) * 256 + tid) * 8) = *(uint4*)ba;
                *(uint4*)(wfrag + ((4 * 2 + ks) * 256 + tid) * 8) = *(uint4*)bb;
                *(uint4*)(wfrag + ((5 * 2 + ks) * 256 + tid) * 8) = *(uint4*)bc;
            }
        }
        // gru2 frags: [g(3)][ks(2)][which(2: 0=Bh,1=Bi)][tid(256)][8];
        // gate rows g=0,1 scaled by log2e, g=2 (n-gate) by 2*log2e.
        {
            const int nw = tid >> 6, c = tid & 15, quad = (tid >> 4) & 3;
            const int j = nw * 16 + c;
#pragma unroll
            for (int g = 0; g < 3; ++g) {
                const float sc = (g == 2) ? 2.f * LOG2E : LOG2E;
                const int row = g * 64 + j;
#pragma unroll
                for (int ks = 0; ks < 2; ++ks) {
                    const float* wp = Whh2 + (row << 6) + ks * 32 + quad * 8;
                    float4 wa = *(const float4*)wp;
                    float4 wb = *(const float4*)(wp + 4);
                    ushort_t tmp[8];
                    tmp[0] = fbf(wa.x * sc); tmp[1] = fbf(wa.y * sc);
                    tmp[2] = fbf(wa.z * sc); tmp[3] = fbf(wa.w * sc);
                    tmp[4] = fbf(wb.x * sc); tmp[5] = fbf(wb.y * sc);
                    tmp[6] = fbf(wb.z * sc); tmp[7] = fbf(wb.w * sc);
                    *(uint4*)(g2frag + (((g * 2 + ks) * 2 + 0) * 256 + tid) * 8) = *(uint4*)tmp;
                    const float* wp2 = Wih2 + (row << 6) + ks * 32 + quad * 8;
                    float4 va = *(const float4*)wp2;
                    float4 vb = *(const float4*)(wp2 + 4);
                    tmp[0] = fbf(va.x * sc); tmp[1] = fbf(va.y * sc);
                    tmp[2] = fbf(va.z * sc); tmp[3] = fbf(va.w * sc);
                    tmp[4] = fbf(vb.x * sc); tmp[5] = fbf(vb.y * sc);
                    tmp[6] = fbf(vb.z * sc); tmp[7] = fbf(vb.w * sc);
                    *(uint4*)(g2frag + (((g * 2 + ks) * 2 + 1) * 256 + tid) * 8) = *(uint4*)tmp;
                }
            }
        }
        return;
    }

    if (bx == 1000) {
        // ========== CSR build (single block, int4-vectorized loads) ========
        for (int k = tid; k < NNODE; k += 256) hist[k] = 0;
        if (tid < 64) dh[tid] = 0;
        __syncthreads();
        for (int it = 0; it < 16; ++it) {
            const int e0 = it * 1024 + tid * 4;
            if (e0 + 3 < NEDGE) {
                int4 v4 = *(const int4*)(edges + NEDGE + e0);
                atomicAdd(&hist[v4.x], 1);
                atomicAdd(&hist[v4.y], 1);
                atomicAdd(&hist[v4.z], 1);
                atomicAdd(&hist[v4.w], 1);
            } else {
#pragma unroll
                for (int k = 0; k < 4; ++k) {
                    const int e = e0 + k;
                    if (e < NEDGE) atomicAdd(&hist[edges[NEDGE + e]], 1);
                }
            }
        }
        __syncthreads();
        const int lane = tid & 63, w = tid >> 6;
        int d[8];
        int s = 0;
#pragma unroll
        for (int q = 0; q < 8; ++q) {
            const int idx = tid * 8 + q;
            d[q] = (idx < NNODE) ? hist[idx] : 0;
            s += d[q];
        }
        int v = s;
#pragma unroll
        for (int off = 1; off < 64; off <<= 1) {
            int u = __shfl_up(v, off);
            if (lane >= off) v += u;
        }
        if (lane == 63) wsum[w] = v;
        __syncthreads();
        int base = 0;
        for (int k = 0; k < 4; ++k) if (k < w) base += wsum[k];
        int run = base + v - s;
        int rs8[8];
#pragma unroll
        for (int q = 0; q < 8; ++q) {
            const int idx = tid * 8 + q;
            if (idx < NNODE) {
                rs8[q] = run;
                rowstart[idx] = run;
                degree[idx] = d[q];
                run += d[q];
                atomicAdd(&dh[63 - min(d[q], 63)], 1);   // descending-degree key
            }
        }
        __syncthreads();
        if (tid == 0) {          // serial prefix over 64 buckets
            int acc = 0;
            for (int k = 0; k < 64; ++k) { const int c = dh[k]; dh[k] = acc; acc += c; }
        }
        __syncthreads();
        // scatter nodes into order[] (longest first)
#pragma unroll
        for (int q = 0; q < 8; ++q) {
            const int idx = tid * 8 + q;
            if (idx < NNODE) {
                const int pos = atomicAdd(&dh[63 - min(d[q], 63)], 1);
                order[pos] = idx;
            }
        }
        // reuse hist as scatter cursor
        __syncthreads();
#pragma unroll
        for (int q = 0; q < 8; ++q) {
            const int idx = tid * 8 + q;
            if (idx < NNODE) hist[idx] = rs8[q];
        }
        __syncthreads();
        for (int it = 0; it < 16; ++it) {
            const int e0 = it * 1024 + tid * 4;
            if (e0 + 3 < NEDGE) {
                int4 dv4 = *(const int4*)(edges + NEDGE + e0);
                int4 sv4 = *(const int4*)(edges + e0);
                int pos;
                pos = atomicAdd(&hist[dv4.x], 1); srcids[pos] = sv4.x; eids[pos] = e0;
                pos = atomicAdd(&hist[dv4.y], 1); srcids[pos] = sv4.y; eids[pos] = e0 + 1;
                pos = atomicAdd(&hist[dv4.z], 1); srcids[pos] = sv4.z; eids[pos] = e0 + 2;
                pos = atomicAdd(&hist[dv4.w], 1); srcids[pos] = sv4.w; eids[pos] = e0 + 3;
            } else {
#pragma unroll
                for (int k = 0; k < 4; ++k) {
                    const int e = e0 + k;
                    if (e < NEDGE) {
                        const int pos = atomicAdd(&hist[edges[NEDGE + e]], 1);
                        srcids[pos] = edges[e];
                        eids[pos] = e;
                    }
                }
            }
        }
        return;
    }

    if (bx > 1000) {
        // ============ alpha MLP (4 edges/block, float4 loads) ============
        const int w = tid >> 6, lane = tid & 63;
        const int e = (bx - 1001) * 4 + w;
        int i, j;
        if (e < NEDGE) { j = edges[e]; i = edges[NEDGE + e]; }
        else { i = j = e - NEDGE; }
        const int o = lane >> 2, q = lane & 3;
        const float* fsrc = (q < 2) ? (features + i * 64 + q * 32)
                                    : (features + j * 64 + (q - 2) * 32);
        const float* wsrc = W1 + o * 128 + q * 32;
        const float4* f4 = (const float4*)fsrc;
        const float4* w4 = (const float4*)wsrc;
        float acc = 0.f;
#pragma unroll
        for (int k = 0; k < 8; ++k) {
            float4 a = f4[k], b = w4[k];
            acc = fmaf(a.x, b.x, acc);
            acc = fmaf(a.y, b.y, acc);
            acc = fmaf(a.z, b.z, acc);
            acc = fmaf(a.w, b.w, acc);
        }
        acc += __shfl_xor(acc, 1);
        acc += __shfl_xor(acc, 2);
        if (q == 0) m1[w][o] = sigm(acc + b1[o]);
        __syncthreads();
        if (lane < 32 && e < NEDGE + NNODE) {
            const int o2 = lane >> 4, k = lane & 15;
            float p = m1[w][k] * W2[o2 * 16 + k];
            p += __shfl_xor(p, 1);
            p += __shfl_xor(p, 2);
            p += __shfl_xor(p, 4);
            p += __shfl_xor(p, 8);
            if (k == 0) alphas[e * 2 + o2] = sigm(p + b2[o2]);
        }
        return;
    }

    // ================= GRU1 (blocks 0..999), log2e-folded gates ==========
    const int nw = tid >> 6;
    const int c = tid & 15;
    const int quad = (tid >> 4) & 3;
    const int j = nw * 16 + c;
    const int s0 = bx * 16;
    const int crow = tid >> 4, ccol = (tid & 15) * 4;   // out1 copy mapping (uint2)

    if (tid < 128) *(uint4*)&H[0][tid >> 3][(tid & 7) * 8] = uint4{0, 0, 0, 0};
#pragma unroll
    for (int p = 0; p < 2; ++p) {
        const int flat = p * 256 + tid;
        if (flat < 384) {
            const int sl = flat / 24, q = flat - sl * 24;
            XD[sl][q] = data[(s0 + sl) * 24 + q];
        }
    }

    bf16x8 Bh[3][2];
    float wi0[3], wi1[3], bi[3], bh[3];
#pragma unroll
    for (int g = 0; g < 3; ++g) {
        const float sc = (g == 2) ? 2.f * LOG2E : LOG2E;   // gate pre-scaling
        const int row = g * 64 + j;
        float2 wi = *(const float2*)(Wih + row * 2);
        wi0[g] = wi.x * sc; wi1[g] = wi.y * sc;
        bi[g] = bih[row] * sc; bh[g] = bhh[row] * sc;
#pragma unroll
        for (int ks = 0; ks < 2; ++ks) {
            const float* wp = Whh + (row << 6) + ks * 32 + quad * 8;
            float4 wa = *(const float4*)wp;
            float4 wb = *(const float4*)(wp + 4);
            ushort_t tmp[8];
            tmp[0] = fbf(wa.x * sc); tmp[1] = fbf(wa.y * sc);
            tmp[2] = fbf(wa.z * sc); tmp[3] = fbf(wa.w * sc);
            tmp[4] = fbf(wb.x * sc); tmp[5] = fbf(wb.y * sc);
            tmp[6] = fbf(wb.z * sc); tmp[7] = fbf(wb.w * sc);
            Bh[g][ks] = *(bf16x8*)tmp;
        }
    }

    float hold[4];
#pragma unroll
    for (int rg = 0; rg < 4; ++rg) hold[rg] = 0.f;

    for (int t = 0; t < LSEQ; ++t) {
        __syncthreads();
        const ushort_t (*Hr)[SST] = H[t & 1];
        ushort_t (*Hw)[SST] = H[1 - (t & 1)];
        bf16x8 a0 = *(const bf16x8*)&Hr[c][quad * 8];
        bf16x8 a1 = *(const bf16x8*)&Hr[c][32 + quad * 8];
        // coalesced out1 write of h_{t-1} from the stable read buffer
        if (t > 0)
            *(uint2*)(out1 + (s0 + crow) * (LSEQ * HDIM) + (t - 1) * HDIM + ccol) =
                *(const uint2*)&Hr[crow][ccol];
        f32x4 gh[3];
#pragma unroll
        for (int g = 0; g < 3; ++g) {
            f32x4 acc = {0.f, 0.f, 0.f, 0.f};
            acc = __builtin_amdgcn_mfma_f32_16x16x32_bf16(a0, Bh[g][0], acc, 0, 0, 0);
            acc = __builtin_amdgcn_mfma_f32_16x16x32_bf16(a1, Bh[g][1], acc, 0, 0, 0);
            gh[g] = acc;
        }
#pragma unroll
        for (int rg = 0; rg < 4; ++rg) {
            const int sloc = quad * 4 + rg;
            float2 xp = *(const float2*)&XD[sloc][2 * t];
            float gr = bh[0] + gh[0][rg];
            float gz = bh[1] + gh[1][rg];
            float gn = bh[2] + gh[2][rg];
            float ir = bi[0] + wi0[0] * xp.x + wi1[0] * xp.y;
            float iz = bi[1] + wi0[1] * xp.x + wi1[1] * xp.y;
            float in = bi[2] + wi0[2] * xp.x + wi1[2] * xp.y;
            float r = sigm2(ir + gr);          // args pre-scaled by log2e
            float z = sigm2(iz + gz);
            float n = tanh2(in + r * gn);      // pre-scaled by 2*log2e
            float hv = (1.f - z) * n + z * hold[rg];
            hold[rg] = hv;
            Hw[sloc][j] = fbf(hv);
        }
    }
    __syncthreads();   // final H[LSEQ&1] (= h_{11}) complete
    *(uint2*)(out1 + (s0 + crow) * (LSEQ * HDIM) + (LSEQ - 1) * HDIM + ccol) =
        *(const uint2*)&H[LSEQ & 1][crow][ccol];
#pragma unroll
    for (int rg = 0; rg < 4; ++rg) {
        const int sloc = quad * 4 + rg;
        h1out[(s0 + sloc) * HDIM + j] = hold[rg];
    }
}

// ---------------------------------------------------------------------------
// MetaGAT (R8 = R4 verbatim, the measured-best 80.5us configuration):
// CSR, MFMA, K-split, PAIR-batched, 3-way node split; fixed-B-frag scheme;
// W3/b3 frags precomputed+log2e-scaled; uniform CSR loads software-pipelined
// 1-2 pairs ahead; Sj C-position dword reads; vector prefetch issued AFTER
// the barrier, consumed next iteration (R6/R7 lesson: deeper pipelines and
// bigger batches both regress ~8% -- this placement is the local optimum).
// ---------------------------------------------------------------------------
__global__ __launch_bounds__(256) void gat_csr_kernel(
    const ushort_t* __restrict__ out1,
    const int* __restrict__ degree, const int* __restrict__ rowstart,
    const int* __restrict__ srcids, const int* __restrict__ eids,
    const int* __restrict__ order,
    const float* __restrict__ alphas,
    const ushort_t* __restrict__ wfrag,
    ushort_t* __restrict__ agg)
{
    __shared__ ushort_t POOL[4][32][SST] __attribute__((aligned(16)));  // 18432 B

    const int tid = threadIdx.x;
    const int i = order[blockIdx.x];      // degree-descending schedule
    const int mh = blockIdx.y;            // M-third
    const int deg = degree[i];
    const int rs = rowstart[i];

    const int wv = tid >> 6;              // N-strip
    const int r = tid & 15;
    const int quad = (tid >> 4) & 3;
    const int n = wv * 16 + r;

    // self-loop alpha: issue early (uniform s_load, consumed after preamble)
    const float2 aSelf = *(const float2*)(alphas + (NEDGE + i) * 2);

    // ---- precomputed invariant offsets ----
    int glo[2], lso[2];
#pragma unroll
    for (int p = 0; p < 2; ++p) {
        const int u = p * 256 + tid;
        const int rr = u >> 4, c4 = u & 15;
        const int b = rr & 7, l = (rr >> 3) + 4 * mh;
        glo[p] = (b * 12 + l) * 64 + c4 * 4;
        lso[p] = rr * SST + c4 * 4;
    }
    int afo[2][2];
#pragma unroll
    for (int mt = 0; mt < 2; ++mt) {
        afo[mt][0] = (mt * 16 + r) * SST + quad * 8;
        afo[mt][1] = afo[mt][0] + 32;
    }
    // C-position dword base offsets (ushort units, even): rows quad*4+g2,
    // col pair n&~1. g2 strides are +SST ushorts = +36 dwords.
    int cbo[2];
#pragma unroll
    for (int mt = 0; mt < 2; ++mt)
        cbo[mt] = (mt * 16 + quad * 4) * SST + (n & ~1);
    const uint_t shamt = (n & 1) ? 0u : 16u;   // bf16 in hi/lo half of dword

    const ushort_t* pi = out1 + i * (NB * LSEQ * HDIM);
    ushort_t* const sbase = &POOL[0][0][0];
    ushort_t* const Si = sbase;           // slot 0 doubles as Si

    // ---- stage Si (slot 0) ----
#pragma unroll
    for (int p = 0; p < 2; ++p)
        *(uint2*)(Si + lso[p]) = *(const uint2*)(pi + glo[p]);

    // ---- fixed B-frags: 12 coalesced dwordx4 loads from precompute table ----
    bf16x8 WtA[2], WtB[2], WtC[2], WbA[2], WbB[2], WbC[2];
#pragma unroll
    for (int ks = 0; ks < 2; ++ks) {
        WtA[ks] = *(const bf16x8*)(wfrag + ((0 * 2 + ks) * 256 + tid) * 8);
        WtB[ks] = *(const bf16x8*)(wfrag + ((1 * 2 + ks) * 256 + tid) * 8);
        WtC[ks] = *(const bf16x8*)(wfrag + ((2 * 2 + ks) * 256 + tid) * 8);
        WbA[ks] = *(const bf16x8*)(wfrag + ((3 * 2 + ks) * 256 + tid) * 8);
        WbB[ks] = *(const bf16x8*)(wfrag + ((4 * 2 + ks) * 256 + tid) * 8);
        WbC[ks] = *(const bf16x8*)(wfrag + ((5 * 2 + ks) * 256 + tid) * 8);
    }

    __syncthreads();   // Si ready

    // ---- preamble: Si-projections PA/PB/PC ----
    f32x4 PA[2], PB[2], PC[2];
#pragma unroll
    for (int mt = 0; mt < 2; ++mt) {
        bf16x8 af0 = *(const bf16x8*)(Si + afo[mt][0]);
        bf16x8 af1 = *(const bf16x8*)(Si + afo[mt][1]);
        f32x4 pa = {0.f, 0.f, 0.f, 0.f};
        f32x4 pb = {0.f, 0.f, 0.f, 0.f};
        f32x4 pc = {0.f, 0.f, 0.f, 0.f};
        pa = __builtin_amdgcn_mfma_f32_16x16x32_bf16(af0, WtA[0], pa, 0, 0, 0);
        pa = __builtin_amdgcn_mfma_f32_16x16x32_bf16(af1, WtA[1], pa, 0, 0, 0);
        pb = __builtin_amdgcn_mfma_f32_16x16x32_bf16(af0, WtB[0], pb, 0, 0, 0);
        pb = __builtin_amdgcn_mfma_f32_16x16x32_bf16(af1, WtB[1], pb, 0, 0, 0);
        pc = __builtin_amdgcn_mfma_f32_16x16x32_bf16(af0, WtC[0], pc, 0, 0, 0);
        pc = __builtin_amdgcn_mfma_f32_16x16x32_bf16(af1, WtC[1], pc, 0, 0, 0);
        PA[mt] = pa; PB[mt] = pb; PC[mt] = pc;
    }

    float accN[2][4];
#pragma unroll
    for (int mt = 0; mt < 2; ++mt)
#pragma unroll
        for (int g2 = 0; g2 < 4; ++g2) accN[mt][g2] = 0.f;

    auto process = [&](const ushort_t* SB, float2 a01) {
#pragma unroll
        for (int mt = 0; mt < 2; ++mt) {
            bf16x8 aj0 = *(const bf16x8*)(SB + afo[mt][0]);
            bf16x8 aj1 = *(const bf16x8*)(SB + afo[mt][1]);
            // C-position Sj dwords (rows g2=0..3): ds_read2_b32-formable
            const uint_t* dp = (const uint_t*)(SB + cbo[mt]);
            uint_t d0 = dp[0], d1 = dp[36], d2 = dp[72], d3 = dp[108];
            f32x4 aA = PA[mt], aB = PB[mt], aC = PC[mt];
            aA = __builtin_amdgcn_mfma_f32_16x16x32_bf16(aj0, WbA[0], aA, 0, 0, 0);
            aA = __builtin_amdgcn_mfma_f32_16x16x32_bf16(aj1, WbA[1], aA, 0, 0, 0);
            aB = __builtin_amdgcn_mfma_f32_16x16x32_bf16(aj0, WbB[0], aB, 0, 0, 0);
            aB = __builtin_amdgcn_mfma_f32_16x16x32_bf16(aj1, WbB[1], aB, 0, 0, 0);
            aC = __builtin_amdgcn_mfma_f32_16x16x32_bf16(aj0, WbC[0], aC, 0, 0, 0);
            aC = __builtin_amdgcn_mfma_f32_16x16x32_bf16(aj1, WbC[1], aC, 0, 0, 0);
            float v[4];
            float s = 0.f;
#pragma unroll
            for (int g2 = 0; g2 < 4; ++g2) {
                // frags pre-scaled by log2e -> exp2 direct; leaky commutes
                float x = fmaf(a01.x, aA[g2], fmaf(a01.y, aB[g2], aC[g2]));
                x = fmaxf(x, 0.01f * x);       // leaky_relu
                v[g2] = __builtin_amdgcn_exp2f(x);
                s += v[g2];
            }
            s += __shfl_xor(s, 16);
            const float inv = __builtin_amdgcn_rcpf(s);
            uint_t dd[4] = {d0, d1, d2, d3};
#pragma unroll
            for (int g2 = 0; g2 < 4; ++g2) {
                const float sj = __uint_as_float((dd[g2] << shamt) & 0xFFFF0000u);
                accN[mt][g2] += v[g2] * inv * sj;
            }
        }
    };

    // ---- uniform CSR metadata pipeline (SGPR-resident) ----
    int sa_nxt = 0, sb_nxt = 0, eA1 = 0, eB1 = 0;
    float2 aA_cur = float2{0.f, 0.f}, aB_cur = float2{0.f, 0.f};
    if (deg >= 1) { const int e = eids[rs];     aA_cur = *(const float2*)(alphas + e * 2); }
    if (deg >= 2) { const int e = eids[rs + 1]; aB_cur = *(const float2*)(alphas + e * 2); }
    if (deg >= 3) { sa_nxt = srcids[rs + 2]; eA1 = eids[rs + 2]; }
    if (deg >= 4) { sb_nxt = srcids[rs + 3]; eB1 = eids[rs + 3]; }

    // ---- vector prefetch CSR edges 0,1 into registers ----
    uint2 pfA[2], pfB[2];
    {
        const ushort_t* pA = out1 + ((deg >= 1) ? srcids[rs] : 0) * (NB * LSEQ * HDIM);
        const ushort_t* pB = out1 + ((deg >= 2) ? srcids[rs + 1] : 0) * (NB * LSEQ * HDIM);
#pragma unroll
        for (int p = 0; p < 2; ++p) {
            pfA[p] = *(const uint2*)(pA + glo[p]);
            pfB[p] = *(const uint2*)(pB + glo[p]);
        }
    }

    // ---- self loop (reads slot 0 = Si) ----
    process(Si, aSelf);
    __syncthreads();   // all waves done reading Si before pair 0 overwrites it

    const int npairs = (deg + 1) >> 1;
    for (int pk = 0; pk < npairs; ++pk) {
        ushort_t* SA = sbase + (2 * (pk & 1)) * (32 * SST);
        ushort_t* SB = SA + 32 * SST;
#pragma unroll
        for (int p = 0; p < 2; ++p) {
            *(uint2*)(SA + lso[p]) = pfA[p];
            *(uint2*)(SB + lso[p]) = pfB[p];
        }
        const int base = pk * 2;
        const bool hasB = (base + 1) < deg;

        // issue next-next uniform loads: srcids/eids for pair pk+2,
        // alphas for pair pk+1 (eids loaded last iteration -> no chained stall)
        int sa_n2 = 0, sb_n2 = 0, eA2 = 0, eB2 = 0;
        if (base + 4 < deg) { sa_n2 = srcids[rs + base + 4]; eA2 = eids[rs + base + 4]; }
        if (base + 5 < deg) { sb_n2 = srcids[rs + base + 5]; eB2 = eids[rs + base + 5]; }
        float2 aA_n = float2{0.f, 0.f}, aB_n = float2{0.f, 0.f};
        if (base + 2 < deg) aA_n = *(const float2*)(alphas + eA1 * 2);
        if (base + 3 < deg) aB_n = *(const float2*)(alphas + eB1 * 2);

        __syncthreads();   // pair tiles ready (pk-1 slots fully read pre-barrier)

        // vector prefetch for edges base+2,3 (addresses from LAST iteration)
        if (base + 2 < deg) {
            const ushort_t* pA = out1 + sa_nxt * (NB * LSEQ * HDIM);
#pragma unroll
            for (int p = 0; p < 2; ++p) pfA[p] = *(const uint2*)(pA + glo[p]);
        }
        if (base + 3 < deg) {
            const ushort_t* pB = out1 + sb_nxt * (NB * LSEQ * HDIM);
#pragma unroll
            for (int p = 0; p < 2; ++p) pfB[p] = *(const uint2*)(pB + glo[p]);
        }

        process(SA, aA_cur);
        if (hasB) process(SB, aB_cur);

        // rotate pipeline registers
        aA_cur = aA_n; aB_cur = aB_n;
        sa_nxt = sa_n2; sb_nxt = sb_n2;
        eA1 = eA2; eB1 = eB2;
    }

    // single non-atomic bf16 store of this third-node's aggregate
#pragma unroll
    for (int mt = 0; mt < 2; ++mt)
#pragma unroll
        for (int g2 = 0; g2 < 4; ++g2) {
            const int gr = mh * 32 + mt * 16 + quad * 4 + g2;  // = l*8 + b
            const int b = gr & 7, l = gr >> 3;
            agg[(i * 96 + b * 12 + l) * 64 + n] = fbf(accN[mt][g2]);
        }
}

// ---------------------------------------------------------------------------
// GRU2 (R4 structure + log2e-folded gates): gi AND gh via MFMA; x = relu(agg
// bf16); 16 seqs / 4 waves per block; H+X ping-pong; next x prefetched under
// MFMAs. Weight frags precomputed AND gate-row pre-scaled (mega bx 5501).
// ---------------------------------------------------------------------------
__global__ __launch_bounds__(256) void gru2_kernel(
    const ushort_t* __restrict__ agg, const ushort_t* __restrict__ g2frag,
    const float* __restrict__ bih, const float* __restrict__ bhh,
    float* __restrict__ h2out)
{
    __shared__ ushort_t H[2][16][SST] __attribute__((aligned(16)));
    __shared__ ushort_t X[2][16][SST] __attribute__((aligned(16)));

    const int tid = threadIdx.x;
    const int nw = tid >> 6;
    const int c = tid & 15;
    const int quad = (tid >> 4) & 3;
    const int j = nw * 16 + c;
    const int s0 = blockIdx.x * 16;
    const int sl = tid >> 3, k0 = (tid & 7) * 8;

    if (tid < 128) *(uint4*)&H[0][tid >> 3][(tid & 7) * 8] = uint4{0, 0, 0, 0};

    bf16x8 Bh[3][2], Bi[3][2];
    float bi[3], bh[3];
#pragma unroll
    for (int g = 0; g < 3; ++g) {
        const float sc = (g == 2) ? 2.f * LOG2E : LOG2E;
        const int row = g * 64 + j;
        bi[g] = bih[row] * sc; bh[g] = bhh[row] * sc;
#pragma unroll
        for (int ks = 0; ks < 2; ++ks) {
            Bh[g][ks] = *(const bf16x8*)(g2frag + (((g * 2 + ks) * 2 + 0) * 256 + tid) * 8);
            Bi[g][ks] = *(const bf16x8*)(g2frag + (((g * 2 + ks) * 2 + 1) * 256 + tid) * 8);
        }
    }

    float hold[4];
#pragma unroll
    for (int rg = 0; rg < 4; ++rg) hold[rg] = 0.f;

    if (tid < 128) {
        ushort_t xr[8];
        *(uint4*)xr = *(const uint4*)(agg + (s0 + sl) * (LSEQ * HDIM) + k0);
        ushort_t xs[8];
#pragma unroll
        for (int q = 0; q < 8; ++q) xs[q] = (xr[q] & 0x8000u) ? (ushort_t)0 : xr[q];
        *(uint4*)&X[0][sl][k0] = *(uint4*)xs;
    }

    for (int t = 0; t < LSEQ; ++t) {
        __syncthreads();
        const int rb = t & 1, wb = 1 - rb;
        bf16x8 ah0 = *(const bf16x8*)&H[rb][c][quad * 8];
        bf16x8 ah1 = *(const bf16x8*)&H[rb][c][32 + quad * 8];
        bf16x8 ax0 = *(const bf16x8*)&X[rb][c][quad * 8];
        bf16x8 ax1 = *(const bf16x8*)&X[rb][c][32 + quad * 8];

        ushort_t xr[8];
        if (t < LSEQ - 1 && tid < 128)
            *(uint4*)xr = *(const uint4*)(agg + (s0 + sl) * (LSEQ * HDIM) +
                                          (t + 1) * HDIM + k0);

        f32x4 gh[3], gi[3];
#pragma unroll
        for (int g = 0; g < 3; ++g) {
            f32x4 acc = {0.f, 0.f, 0.f, 0.f};
            acc = __builtin_amdgcn_mfma_f32_16x16x32_bf16(ah0, Bh[g][0], acc, 0, 0, 0);
            acc = __builtin_amdgcn_mfma_f32_16x16x32_bf16(ah1, Bh[g][1], acc, 0, 0, 0);
            gh[g] = acc;
            f32x4 acc2 = {0.f, 0.f, 0.f, 0.f};
            acc2 = __builtin_amdgcn_mfma_f32_16x16x32_bf16(ax0, Bi[g][0], acc2, 0, 0, 0);
            acc2 = __builtin_amdgcn_mfma_f32_16x16x32_bf16(ax1, Bi[g][1], acc2, 0, 0, 0);
            gi[g] = acc2;
        }
#pragma unroll
        for (int rg = 0; rg < 4; ++rg) {
            const int sloc = quad * 4 + rg;
            float r = sigm2(bi[0] + gi[0][rg] + bh[0] + gh[0][rg]);
            float z = sigm2(bi[1] + gi[1][rg] + bh[1] + gh[1][rg]);
            float n = tanh2(bi[2] + gi[2][rg] + r * (bh[2] + gh[2][rg]));
            float hv = (1.f - z) * n + z * hold[rg];
            hold[rg] = hv;
            H[wb][sloc][j] = fbf(hv);
        }
        if (t < LSEQ - 1 && tid < 128) {
            ushort_t xs[8];
#pragma unroll
            for (int q = 0; q < 8; ++q) xs[q] = (xr[q] & 0x8000u) ? (ushort_t)0 : xr[q];
            *(uint4*)&X[wb][sl][k0] = *(uint4*)xs;
        }
    }
#pragma unroll
    for (int rg = 0; rg < 4; ++rg) {
        const int sloc = quad * 4 + rg;
        h2out[(s0 + sloc) * HDIM + j] = hold[rg];
    }
}

extern "C" void kernel_launch(void* const* d_in, const int* in_sizes, int n_in,
                              void* d_out, int out_size, void* d_ws, size_t ws_size,
                              hipStream_t stream)
{
    const float* data     = (const float*)d_in[0];
    const float* features = (const float*)d_in[1];
    const int*   edges    = (const int*)d_in[2];
    const float* Wih1     = (const float*)d_in[3];
    const float* Whh1     = (const float*)d_in[4];
    const float* bih1     = (const float*)d_in[5];
    const float* bhh1     = (const float*)d_in[6];
    const float* W1       = (const float*)d_in[7];
    const float* b1       = (const float*)d_in[8];
    const float* W2       = (const float*)d_in[9];
    const float* b2       = (const float*)d_in[10];
    const float* W3       = (const float*)d_in[11];
    const float* b3       = (const float*)d_in[12];
    const float* Wih2     = (const float*)d_in[13];
    const float* Whh2     = (const float*)d_in[14];
    const float* bih2     = (const float*)d_in[15];
    const float* bhh2     = (const float*)d_in[16];

    float*    out  = (float*)d_out;
    char*     ws   = (char*)d_ws;
    ushort_t* out1 = (ushort_t*)ws;                    // bf16 intermediate
    ushort_t* agg  = (ushort_t*)(ws + OUT1_BYTES);     // bf16 GAT output
    int*      meta = (int*)(ws + OUT1_BYTES + AGG_BYTES);
    int*   degree   = meta;                                 // [2000]
    int*   rowstart = meta + NNODE;                         // [2000]
    int*   srcids   = meta + 2 * NNODE;                     // [16000]
    int*   eids     = meta + 2 * NNODE + NEDGE;             // [16000]
    int*   order    = meta + 2 * NNODE + 2 * NEDGE;         // [2000]
    float* alphas   = (float*)(meta + 3 * NNODE + 2 * NEDGE);  // [36000]
    ushort_t* wfrag  = (ushort_t*)((char*)alphas + 36000 * 4); // [24576] 16B-aligned
    ushort_t* g2frag = wfrag + WFRAG_ELEMS;                    // [24576]

    // 3 dispatches: mega (gru1 || csr || alpha || frag-precompute), gat, gru2.
    mega_kernel<<<1001 + 4500 + 1, 256, 0, stream>>>(
        data, Wih1, Whh1, bih1, bhh1, out1, out,
        edges, degree, rowstart, srcids, eids, order,
        features, W1, b1, W2, b2, alphas,
        W3, b3, Wih2, Whh2, wfrag, g2frag);
    gat_csr_kernel<<<dim3(NNODE, 3), 256, 0, stream>>>(out1, degree, rowstart, srcids,
                                                       eids, order, alphas, wfrag, agg);
    gru2_kernel<<<NSEQ / 16, 256, 0, stream>>>(agg, g2frag, bih2, bhh2,
                                               out + NNODE * NB * HDIM);
}

// Round 9
// 224.720 us; speedup vs baseline: 1.0361x; 1.0074x over previous
//
#include <hip/hip_runtime.h>
#include <hip/hip_bf16.h>

typedef unsigned short ushort_t;
typedef unsigned int uint_t;
typedef __attribute__((ext_vector_type(8))) short bf16x8;
typedef __attribute__((ext_vector_type(4))) float f32x4;

#define NNODE 2000
#define NB 8
#define LSEQ 12
#define HDIM 64
#define NEDGE 16000
#define NSEQ (NNODE * NB)            // 16000 sequences
#define OUT1_ELEMS (NNODE * NB * LSEQ * HDIM)   // 12,288,000
#define OUT1_BYTES (OUT1_ELEMS * 2)             // bf16: 24,576,000
#define AGG_BYTES  (OUT1_ELEMS * 2)             // bf16: 24,576,000
// LDS row stride: multiple of 8 elems (16 B) for ds_read_b128 (R17 lesson).
#define SST 72
#define LOG2E 1.4426950408889634f

// precomputed-fragment table sizes (ushort counts)
#define WFRAG_ELEMS (6 * 2 * 256 * 8)   // gat W3/b3 frags: 24576 (49,152 B)
#define G2FRAG_ELEMS (3 * 2 * 2 * 256 * 8) // gru2 Whh/Wih frags: 24576 (49,152 B)

__device__ __forceinline__ float bf1(ushort_t u) { return __uint_as_float(((uint_t)u) << 16); }
__device__ __forceinline__ ushort_t fbf(float f) {
    uint_t x = __float_as_uint(f);
    uint_t r = x + 0x7fffu + ((x >> 16) & 1u);   // RNE
    return (ushort_t)(r >> 16);
}
// rcp instead of IEEE divide (R2 win): 1 inst vs ~10-inst div sequence.
__device__ __forceinline__ float sigm(float x) {
    return __builtin_amdgcn_rcpf(1.f + __expf(-x));
}
// log2e-folded variants: argument is PRE-SCALED by log2e (sigm2) or
// 2*log2e (tanh2) via the weight/bias tables -- saves the v_mul inside
// every __expf on the serial gate chain (same mechanism as R2's -14.7us).
__device__ __forceinline__ float sigm2(float x) {
    return __builtin_amdgcn_rcpf(1.f + __builtin_amdgcn_exp2f(-x));
}
__device__ __forceinline__ float tanh2(float x) {
    return 2.f * __builtin_amdgcn_rcpf(1.f + __builtin_amdgcn_exp2f(-x)) - 1.f;
}

// ===========================================================================
// MFMA geometry (HW-verified R3): A[m=lane&15][k=quad*8+jj];
// B[k=ks*32+quad*8+jj][n=lane&15]; C row(M)=quad*4+reg, col(N)=lane&15.
// ===========================================================================

// ---------------------------------------------------------------------------
// MEGA kernel (R8 structure; R9 = CSR-only changes):
//   bx 0..999    = GRU1 (log2e-folded gates)
//   bx 1000      = CSR build: rank-trick (pass-2 atomic-free, R5-validated)
//                  + fused int2 pairs[] (srcid,eid) -- halves pass-2
//                  scattered-store line-touches and gat's uniform loads
//   bx 1001..5500 = alpha MLP (float4 loads)
//   bx 5501      = bf16 fragment precompute
// ---------------------------------------------------------------------------
__global__ __launch_bounds__(256) void mega_kernel(
    const float* __restrict__ data, const float* __restrict__ Wih,
    const float* __restrict__ Whh, const float* __restrict__ bih,
    const float* __restrict__ bhh, ushort_t* __restrict__ out1,
    float* __restrict__ h1out,
    const int* __restrict__ edges, int* __restrict__ degree,
    int* __restrict__ rowstart, int2* __restrict__ pairs,
    int* __restrict__ order, int* __restrict__ rank_,
    const float* __restrict__ features,
    const float* __restrict__ W1, const float* __restrict__ b1,
    const float* __restrict__ W2, const float* __restrict__ b2,
    float* __restrict__ alphas,
    const float* __restrict__ W3, const float* __restrict__ b3,
    const float* __restrict__ Wih2, const float* __restrict__ Whh2,
    ushort_t* __restrict__ wfrag, ushort_t* __restrict__ g2frag)
{
    __shared__ ushort_t H[2][16][SST] __attribute__((aligned(16)));
    __shared__ float XD[16][26];
    __shared__ int hist[NNODE];
    __shared__ int wsum[4];
    __shared__ float m1[4][16];
    __shared__ int dh[64];

    const int bx = blockIdx.x;
    const int tid = threadIdx.x;

    if (bx == 5501) {
        // ============ fragment precompute (once per launch) =============
        // gat frags: layout [arr(6)][ks(2)][tid(256)][8 bf16], scaled by log2e
        {
            const int wv = tid >> 6, r = tid & 15, quad = (tid >> 4) & 3;
            const int n = wv * 16 + r;
#pragma unroll
            for (int ks = 0; ks < 2; ++ks) {
                ushort_t ta[8], tb[8], tc[8], ba[8], bb[8], bc[8];
#pragma unroll
                for (int jj = 0; jj < 8; ++jj) {
                    const int mt_ = (ks * 32 + quad * 8 + jj) * 64 + n;
                    float2 w2 = ((const float2*)W3)[mt_];
                    ta[jj] = fbf(w2.x * LOG2E); tb[jj] = fbf(w2.y * LOG2E);
                    tc[jj] = fbf(b3[mt_] * LOG2E);
                    const int mb_ = (64 + ks * 32 + quad * 8 + jj) * 64 + n;
                    float2 w2b = ((const float2*)W3)[mb_];
                    ba[jj] = fbf(w2b.x * LOG2E); bb[jj] = fbf(w2b.y * LOG2E);
                    bc[jj] = fbf(b3[mb_] * LOG2E);
                }
                *(uint4*)(wfrag + ((0 * 2 + ks) * 256 + tid) * 8) = *(uint4*)ta;
                *(uint4*)(wfrag + ((1 * 2 + ks) * 256 + tid) * 8) = *(uint4*)tb;
                *(uint4*)(wfrag + ((2 * 2 + ks) * 256 + tid) * 8) = *(uint4*)tc;
                *(uint4*)(wfrag + ((3 * 2 + ks) * 256 + tid) * 8) = *(uint4*)ba;
                *(uint4*)(wfrag + ((4 * 2 + ks) * 256 + tid) * 8) = *(uint4*)bb;
                *(uint4*)(wfrag + ((5 * 2 + ks) * 256 + tid) * 8) = *(uint4*)bc;
            }
        }
        // gru2 frags: [g(3)][ks(2)][which(2: 0=Bh,1=Bi)][tid(256)][8];
        // gate rows g=0,1 scaled by log2e, g=2 (n-gate) by 2*log2e.
        {
            const int nw = tid >> 6, c = tid & 15, quad = (tid >> 4) & 3;
            const int j = nw * 16 + c;
#pragma unroll
            for (int g = 0; g < 3; ++g) {
                const float sc = (g == 2) ? 2.f * LOG2E : LOG2E;
                const int row = g * 64 + j;
#pragma unroll
                for (int ks = 0; ks < 2; ++ks) {
                    const float* wp = Whh2 + (row << 6) + ks * 32 + quad * 8;
                    float4 wa = *(const float4*)wp;
                    float4 wb = *(const float4*)(wp + 4);
                    ushort_t tmp[8];
                    tmp[0] = fbf(wa.x * sc); tmp[1] = fbf(wa.y * sc);
                    tmp[2] = fbf(wa.z * sc); tmp[3] = fbf(wa.w * sc);
                    tmp[4] = fbf(wb.x * sc); tmp[5] = fbf(wb.y * sc);
                    tmp[6] = fbf(wb.z * sc); tmp[7] = fbf(wb.w * sc);
                    *(uint4*)(g2frag + (((g * 2 + ks) * 2 + 0) * 256 + tid) * 8) = *(uint4*)tmp;
                    const float* wp2 = Wih2 + (row << 6) + ks * 32 + quad * 8;
                    float4 va = *(const float4*)wp2;
                    float4 vb = *(const float4*)(wp2 + 4);
                    tmp[0] = fbf(va.x * sc); tmp[1] = fbf(va.y * sc);
                    tmp[2] = fbf(va.z * sc); tmp[3] = fbf(va.w * sc);
                    tmp[4] = fbf(vb.x * sc); tmp[5] = fbf(vb.y * sc);
                    tmp[6] = fbf(vb.z * sc); tmp[7] = fbf(vb.w * sc);
                    *(uint4*)(g2frag + (((g * 2 + ks) * 2 + 1) * 256 + tid) * 8) = *(uint4*)tmp;
                }
            }
        }
        return;
    }

    if (bx == 1000) {
        // ========== CSR build: rank-trick + fused pairs ====================
        for (int k = tid; k < NNODE; k += 256) hist[k] = 0;
        if (tid < 64) dh[tid] = 0;
        __syncthreads();
        // pass 1: histogram; store per-edge rank (atomicAdd return)
        for (int it = 0; it < 16; ++it) {
            const int e0 = it * 1024 + tid * 4;
            if (e0 + 3 < NEDGE) {
                int4 v4 = *(const int4*)(edges + NEDGE + e0);
                int4 rk;
                rk.x = atomicAdd(&hist[v4.x], 1);
                rk.y = atomicAdd(&hist[v4.y], 1);
                rk.z = atomicAdd(&hist[v4.z], 1);
                rk.w = atomicAdd(&hist[v4.w], 1);
                *(int4*)(rank_ + e0) = rk;
            } else {
#pragma unroll
                for (int k = 0; k < 4; ++k) {
                    const int e = e0 + k;
                    if (e < NEDGE) rank_[e] = atomicAdd(&hist[edges[NEDGE + e]], 1);
                }
            }
        }
        __syncthreads();
        const int lane = tid & 63, w = tid >> 6;
        int d[8];
        int s = 0;
#pragma unroll
        for (int q = 0; q < 8; ++q) {
            const int idx = tid * 8 + q;
            d[q] = (idx < NNODE) ? hist[idx] : 0;
            s += d[q];
        }
        int v = s;
#pragma unroll
        for (int off = 1; off < 64; off <<= 1) {
            int u = __shfl_up(v, off);
            if (lane >= off) v += u;
        }
        if (lane == 63) wsum[w] = v;
        __syncthreads();
        int base = 0;
        for (int k = 0; k < 4; ++k) if (k < w) base += wsum[k];
        int run = base + v - s;
        int rs8[8];
#pragma unroll
        for (int q = 0; q < 8; ++q) {
            const int idx = tid * 8 + q;
            if (idx < NNODE) {
                rs8[q] = run;
                rowstart[idx] = run;
                degree[idx] = d[q];
                run += d[q];
                atomicAdd(&dh[63 - min(d[q], 63)], 1);   // descending-degree key
            }
        }
        __syncthreads();
        if (tid == 0) {          // serial prefix over 64 buckets
            int acc = 0;
            for (int k = 0; k < 64; ++k) { const int c = dh[k]; dh[k] = acc; acc += c; }
        }
        __syncthreads();
        // scatter nodes into order[] (longest first)
#pragma unroll
        for (int q = 0; q < 8; ++q) {
            const int idx = tid * 8 + q;
            if (idx < NNODE) {
                const int pos = atomicAdd(&dh[63 - min(d[q], 63)], 1);
                order[pos] = idx;
            }
        }
        // hist <- rowstart (read-only base for pass 2)
        __syncthreads();
#pragma unroll
        for (int q = 0; q < 8; ++q) {
            const int idx = tid * 8 + q;
            if (idx < NNODE) hist[idx] = rs8[q];
        }
        __syncthreads();
        // pass 2: atomic-free scatter, pos = rowstart[dst] + rank[e];
        // ONE int2 store per edge (srcid,eid fused)
        for (int it = 0; it < 16; ++it) {
            const int e0 = it * 1024 + tid * 4;
            if (e0 + 3 < NEDGE) {
                int4 dv4 = *(const int4*)(edges + NEDGE + e0);
                int4 sv4 = *(const int4*)(edges + e0);
                int4 rk4 = *(const int4*)(rank_ + e0);
                pairs[hist[dv4.x] + rk4.x] = int2{sv4.x, e0};
                pairs[hist[dv4.y] + rk4.y] = int2{sv4.y, e0 + 1};
                pairs[hist[dv4.z] + rk4.z] = int2{sv4.z, e0 + 2};
                pairs[hist[dv4.w] + rk4.w] = int2{sv4.w, e0 + 3};
            } else {
#pragma unroll
                for (int k = 0; k < 4; ++k) {
                    const int e = e0 + k;
                    if (e < NEDGE)
                        pairs[hist[edges[NEDGE + e]] + rank_[e]] = int2{edges[e], e};
                }
            }
        }
        return;
    }

    if (bx > 1000) {
        // ============ alpha MLP (4 edges/block, float4 loads) ============
        const int w = tid >> 6, lane = tid & 63;
        const int e = (bx - 1001) * 4 + w;
        int i, j;
        if (e < NEDGE) { j = edges[e]; i = edges[NEDGE + e]; }
        else { i = j = e - NEDGE; }
        const int o = lane >> 2, q = lane & 3;
        const float* fsrc = (q < 2) ? (features + i * 64 + q * 32)
                                    : (features + j * 64 + (q - 2) * 32);
        const float* wsrc = W1 + o * 128 + q * 32;
        const float4* f4 = (const float4*)fsrc;
        const float4* w4 = (const float4*)wsrc;
        float acc = 0.f;
#pragma unroll
        for (int k = 0; k < 8; ++k) {
            float4 a = f4[k], b = w4[k];
            acc = fmaf(a.x, b.x, acc);
            acc = fmaf(a.y, b.y, acc);
            acc = fmaf(a.z, b.z, acc);
            acc = fmaf(a.w, b.w, acc);
        }
        acc += __shfl_xor(acc, 1);
        acc += __shfl_xor(acc, 2);
        if (q == 0) m1[w][o] = sigm(acc + b1[o]);
        __syncthreads();
        if (lane < 32 && e < NEDGE + NNODE) {
            const int o2 = lane >> 4, k = lane & 15;
            float p = m1[w][k] * W2[o2 * 16 + k];
            p += __shfl_xor(p, 1);
            p += __shfl_xor(p, 2);
            p += __shfl_xor(p, 4);
            p += __shfl_xor(p, 8);
            if (k == 0) alphas[e * 2 + o2] = sigm(p + b2[o2]);
        }
        return;
    }

    // ================= GRU1 (blocks 0..999), log2e-folded gates ==========
    const int nw = tid >> 6;
    const int c = tid & 15;
    const int quad = (tid >> 4) & 3;
    const int j = nw * 16 + c;
    const int s0 = bx * 16;
    const int crow = tid >> 4, ccol = (tid & 15) * 4;   // out1 copy mapping (uint2)

    if (tid < 128) *(uint4*)&H[0][tid >> 3][(tid & 7) * 8] = uint4{0, 0, 0, 0};
#pragma unroll
    for (int p = 0; p < 2; ++p) {
        const int flat = p * 256 + tid;
        if (flat < 384) {
            const int sl = flat / 24, q = flat - sl * 24;
            XD[sl][q] = data[(s0 + sl) * 24 + q];
        }
    }

    bf16x8 Bh[3][2];
    float wi0[3], wi1[3], bi[3], bh[3];
#pragma unroll
    for (int g = 0; g < 3; ++g) {
        const float sc = (g == 2) ? 2.f * LOG2E : LOG2E;   // gate pre-scaling
        const int row = g * 64 + j;
        float2 wi = *(const float2*)(Wih + row * 2);
        wi0[g] = wi.x * sc; wi1[g] = wi.y * sc;
        bi[g] = bih[row] * sc; bh[g] = bhh[row] * sc;
#pragma unroll
        for (int ks = 0; ks < 2; ++ks) {
            const float* wp = Whh + (row << 6) + ks * 32 + quad * 8;
            float4 wa = *(const float4*)wp;
            float4 wb = *(const float4*)(wp + 4);
            ushort_t tmp[8];
            tmp[0] = fbf(wa.x * sc); tmp[1] = fbf(wa.y * sc);
            tmp[2] = fbf(wa.z * sc); tmp[3] = fbf(wa.w * sc);
            tmp[4] = fbf(wb.x * sc); tmp[5] = fbf(wb.y * sc);
            tmp[6] = fbf(wb.z * sc); tmp[7] = fbf(wb.w * sc);
            Bh[g][ks] = *(bf16x8*)tmp;
        }
    }

    float hold[4];
#pragma unroll
    for (int rg = 0; rg < 4; ++rg) hold[rg] = 0.f;

    for (int t = 0; t < LSEQ; ++t) {
        __syncthreads();
        const ushort_t (*Hr)[SST] = H[t & 1];
        ushort_t (*Hw)[SST] = H[1 - (t & 1)];
        bf16x8 a0 = *(const bf16x8*)&Hr[c][quad * 8];
        bf16x8 a1 = *(const bf16x8*)&Hr[c][32 + quad * 8];
        // coalesced out1 write of h_{t-1} from the stable read buffer
        if (t > 0)
            *(uint2*)(out1 + (s0 + crow) * (LSEQ * HDIM) + (t - 1) * HDIM + ccol) =
                *(const uint2*)&Hr[crow][ccol];
        f32x4 gh[3];
#pragma unroll
        for (int g = 0; g < 3; ++g) {
            f32x4 acc = {0.f, 0.f, 0.f, 0.f};
            acc = __builtin_amdgcn_mfma_f32_16x16x32_bf16(a0, Bh[g][0], acc, 0, 0, 0);
            acc = __builtin_amdgcn_mfma_f32_16x16x32_bf16(a1, Bh[g][1], acc, 0, 0, 0);
            gh[g] = acc;
        }
#pragma unroll
        for (int rg = 0; rg < 4; ++rg) {
            const int sloc = quad * 4 + rg;
            float2 xp = *(const float2*)&XD[sloc][2 * t];
            float gr = bh[0] + gh[0][rg];
            float gz = bh[1] + gh[1][rg];
            float gn = bh[2] + gh[2][rg];
            float ir = bi[0] + wi0[0] * xp.x + wi1[0] * xp.y;
            float iz = bi[1] + wi0[1] * xp.x + wi1[1] * xp.y;
            float in = bi[2] + wi0[2] * xp.x + wi1[2] * xp.y;
            float r = sigm2(ir + gr);          // args pre-scaled by log2e
            float z = sigm2(iz + gz);
            float n = tanh2(in + r * gn);      // pre-scaled by 2*log2e
            float hv = (1.f - z) * n + z * hold[rg];
            hold[rg] = hv;
            Hw[sloc][j] = fbf(hv);
        }
    }
    __syncthreads();   // final H[LSEQ&1] (= h_{11}) complete
    *(uint2*)(out1 + (s0 + crow) * (LSEQ * HDIM) + (LSEQ - 1) * HDIM + ccol) =
        *(const uint2*)&H[LSEQ & 1][crow][ccol];
#pragma unroll
    for (int rg = 0; rg < 4; ++rg) {
        const int sloc = quad * 4 + rg;
        h1out[(s0 + sloc) * HDIM + j] = hold[rg];
    }
}

// ---------------------------------------------------------------------------
// MetaGAT (R9 = R4/R8 structure, the measured-best configuration, with the
// fused int2 pairs[] metadata -- each pipeline level loads ONE 8B record
// instead of two 4B records). All other placement identical to R8.
// ---------------------------------------------------------------------------
__global__ __launch_bounds__(256) void gat_csr_kernel(
    const ushort_t* __restrict__ out1,
    const int* __restrict__ degree, const int* __restrict__ rowstart,
    const int2* __restrict__ pairs,
    const int* __restrict__ order,
    const float* __restrict__ alphas,
    const ushort_t* __restrict__ wfrag,
    ushort_t* __restrict__ agg)
{
    __shared__ ushort_t POOL[4][32][SST] __attribute__((aligned(16)));  // 18432 B

    const int tid = threadIdx.x;
    const int i = order[blockIdx.x];      // degree-descending schedule
    const int mh = blockIdx.y;            // M-third
    const int deg = degree[i];
    const int rs = rowstart[i];

    const int wv = tid >> 6;              // N-strip
    const int r = tid & 15;
    const int quad = (tid >> 4) & 3;
    const int n = wv * 16 + r;

    // self-loop alpha: issue early (uniform s_load, consumed after preamble)
    const float2 aSelf = *(const float2*)(alphas + (NEDGE + i) * 2);

    // ---- precomputed invariant offsets ----
    int glo[2], lso[2];
#pragma unroll
    for (int p = 0; p < 2; ++p) {
        const int u = p * 256 + tid;
        const int rr = u >> 4, c4 = u & 15;
        const int b = rr & 7, l = (rr >> 3) + 4 * mh;
        glo[p] = (b * 12 + l) * 64 + c4 * 4;
        lso[p] = rr * SST + c4 * 4;
    }
    int afo[2][2];
#pragma unroll
    for (int mt = 0; mt < 2; ++mt) {
        afo[mt][0] = (mt * 16 + r) * SST + quad * 8;
        afo[mt][1] = afo[mt][0] + 32;
    }
    // C-position dword base offsets (ushort units, even): rows quad*4+g2,
    // col pair n&~1. g2 strides are +SST ushorts = +36 dwords.
    int cbo[2];
#pragma unroll
    for (int mt = 0; mt < 2; ++mt)
        cbo[mt] = (mt * 16 + quad * 4) * SST + (n & ~1);
    const uint_t shamt = (n & 1) ? 0u : 16u;   // bf16 in hi/lo half of dword

    const ushort_t* pi = out1 + i * (NB * LSEQ * HDIM);
    ushort_t* const sbase = &POOL[0][0][0];
    ushort_t* const Si = sbase;           // slot 0 doubles as Si

    // ---- stage Si (slot 0) ----
#pragma unroll
    for (int p = 0; p < 2; ++p)
        *(uint2*)(Si + lso[p]) = *(const uint2*)(pi + glo[p]);

    // ---- fixed B-frags: 12 coalesced dwordx4 loads from precompute table ----
    bf16x8 WtA[2], WtB[2], WtC[2], WbA[2], WbB[2], WbC[2];
#pragma unroll
    for (int ks = 0; ks < 2; ++ks) {
        WtA[ks] = *(const bf16x8*)(wfrag + ((0 * 2 + ks) * 256 + tid) * 8);
        WtB[ks] = *(const bf16x8*)(wfrag + ((1 * 2 + ks) * 256 + tid) * 8);
        WtC[ks] = *(const bf16x8*)(wfrag + ((2 * 2 + ks) * 256 + tid) * 8);
        WbA[ks] = *(const bf16x8*)(wfrag + ((3 * 2 + ks) * 256 + tid) * 8);
        WbB[ks] = *(const bf16x8*)(wfrag + ((4 * 2 + ks) * 256 + tid) * 8);
        WbC[ks] = *(const bf16x8*)(wfrag + ((5 * 2 + ks) * 256 + tid) * 8);
    }

    __syncthreads();   // Si ready

    // ---- preamble: Si-projections PA/PB/PC ----
    f32x4 PA[2], PB[2], PC[2];
#pragma unroll
    for (int mt = 0; mt < 2; ++mt) {
        bf16x8 af0 = *(const bf16x8*)(Si + afo[mt][0]);
        bf16x8 af1 = *(const bf16x8*)(Si + afo[mt][1]);
        f32x4 pa = {0.f, 0.f, 0.f, 0.f};
        f32x4 pb = {0.f, 0.f, 0.f, 0.f};
        f32x4 pc = {0.f, 0.f, 0.f, 0.f};
        pa = __builtin_amdgcn_mfma_f32_16x16x32_bf16(af0, WtA[0], pa, 0, 0, 0);
        pa = __builtin_amdgcn_mfma_f32_16x16x32_bf16(af1, WtA[1], pa, 0, 0, 0);
        pb = __builtin_amdgcn_mfma_f32_16x16x32_bf16(af0, WtB[0], pb, 0, 0, 0);
        pb = __builtin_amdgcn_mfma_f32_16x16x32_bf16(af1, WtB[1], pb, 0, 0, 0);
        pc = __builtin_amdgcn_mfma_f32_16x16x32_bf16(af0, WtC[0], pc, 0, 0, 0);
        pc = __builtin_amdgcn_mfma_f32_16x16x32_bf16(af1, WtC[1], pc, 0, 0, 0);
        PA[mt] = pa; PB[mt] = pb; PC[mt] = pc;
    }

    float accN[2][4];
#pragma unroll
    for (int mt = 0; mt < 2; ++mt)
#pragma unroll
        for (int g2 = 0; g2 < 4; ++g2) accN[mt][g2] = 0.f;

    auto process = [&](const ushort_t* SB, float2 a01) {
#pragma unroll
        for (int mt = 0; mt < 2; ++mt) {
            bf16x8 aj0 = *(const bf16x8*)(SB + afo[mt][0]);
            bf16x8 aj1 = *(const bf16x8*)(SB + afo[mt][1]);
            // C-position Sj dwords (rows g2=0..3): ds_read2_b32-formable
            const uint_t* dp = (const uint_t*)(SB + cbo[mt]);
            uint_t d0 = dp[0], d1 = dp[36], d2 = dp[72], d3 = dp[108];
            f32x4 aA = PA[mt], aB = PB[mt], aC = PC[mt];
            aA = __builtin_amdgcn_mfma_f32_16x16x32_bf16(aj0, WbA[0], aA, 0, 0, 0);
            aA = __builtin_amdgcn_mfma_f32_16x16x32_bf16(aj1, WbA[1], aA, 0, 0, 0);
            aB = __builtin_amdgcn_mfma_f32_16x16x32_bf16(aj0, WbB[0], aB, 0, 0, 0);
            aB = __builtin_amdgcn_mfma_f32_16x16x32_bf16(aj1, WbB[1], aB, 0, 0, 0);
            aC = __builtin_amdgcn_mfma_f32_16x16x32_bf16(aj0, WbC[0], aC, 0, 0, 0);
            aC = __builtin_amdgcn_mfma_f32_16x16x32_bf16(aj1, WbC[1], aC, 0, 0, 0);
            float v[4];
            float s = 0.f;
#pragma unroll
            for (int g2 = 0; g2 < 4; ++g2) {
                // frags pre-scaled by log2e -> exp2 direct; leaky commutes
                float x = fmaf(a01.x, aA[g2], fmaf(a01.y, aB[g2], aC[g2]));
                x = fmaxf(x, 0.01f * x);       // leaky_relu
                v[g2] = __builtin_amdgcn_exp2f(x);
                s += v[g2];
            }
            s += __shfl_xor(s, 16);
            const float inv = __builtin_amdgcn_rcpf(s);
            uint_t dd[4] = {d0, d1, d2, d3};
#pragma unroll
            for (int g2 = 0; g2 < 4; ++g2) {
                const float sj = __uint_as_float((dd[g2] << shamt) & 0xFFFF0000u);
                accN[mt][g2] += v[g2] * inv * sj;
            }
        }
    };

    // ---- uniform CSR metadata pipeline (SGPR-resident, int2 records) ----
    int sa_nxt = 0, sb_nxt = 0, eA1 = 0, eB1 = 0;
    int s0id = 0, s1id = 0;
    float2 aA_cur = float2{0.f, 0.f}, aB_cur = float2{0.f, 0.f};
    if (deg >= 1) { int2 p = pairs[rs];     s0id = p.x; aA_cur = *(const float2*)(alphas + p.y * 2); }
    if (deg >= 2) { int2 p = pairs[rs + 1]; s1id = p.x; aB_cur = *(const float2*)(alphas + p.y * 2); }
    if (deg >= 3) { int2 p = pairs[rs + 2]; sa_nxt = p.x; eA1 = p.y; }
    if (deg >= 4) { int2 p = pairs[rs + 3]; sb_nxt = p.x; eB1 = p.y; }

    // ---- vector prefetch CSR edges 0,1 into registers ----
    uint2 pfA[2], pfB[2];
    {
        const ushort_t* pA = out1 + s0id * (NB * LSEQ * HDIM);
        const ushort_t* pB = out1 + s1id * (NB * LSEQ * HDIM);
#pragma unroll
        for (int p = 0; p < 2; ++p) {
            pfA[p] = *(const uint2*)(pA + glo[p]);
            pfB[p] = *(const uint2*)(pB + glo[p]);
        }
    }

    // ---- self loop (reads slot 0 = Si) ----
    process(Si, aSelf);
    __syncthreads();   // all waves done reading Si before pair 0 overwrites it

    const int npairs = (deg + 1) >> 1;
    for (int pk = 0; pk < npairs; ++pk) {
        ushort_t* SA = sbase + (2 * (pk & 1)) * (32 * SST);
        ushort_t* SB = SA + 32 * SST;
#pragma unroll
        for (int p = 0; p < 2; ++p) {
            *(uint2*)(SA + lso[p]) = pfA[p];
            *(uint2*)(SB + lso[p]) = pfB[p];
        }
        const int base = pk * 2;
        const bool hasB = (base + 1) < deg;

        // issue next-next uniform loads: pairs for pk+2, alphas for pk+1
        // (eids loaded last iteration -> no chained stall)
        int sa_n2 = 0, sb_n2 = 0, eA2 = 0, eB2 = 0;
        if (base + 4 < deg) { int2 p = pairs[rs + base + 4]; sa_n2 = p.x; eA2 = p.y; }
        if (base + 5 < deg) { int2 p = pairs[rs + base + 5]; sb_n2 = p.x; eB2 = p.y; }
        float2 aA_n = float2{0.f, 0.f}, aB_n = float2{0.f, 0.f};
        if (base + 2 < deg) aA_n = *(const float2*)(alphas + eA1 * 2);
        if (base + 3 < deg) aB_n = *(const float2*)(alphas + eB1 * 2);

        __syncthreads();   // pair tiles ready (pk-1 slots fully read pre-barrier)

        // vector prefetch for edges base+2,3 (addresses from LAST iteration)
        if (base + 2 < deg) {
            const ushort_t* pA = out1 + sa_nxt * (NB * LSEQ * HDIM);
#pragma unroll
            for (int p = 0; p < 2; ++p) pfA[p] = *(const uint2*)(pA + glo[p]);
        }
        if (base + 3 < deg) {
            const ushort_t* pB = out1 + sb_nxt * (NB * LSEQ * HDIM);
#pragma unroll
            for (int p = 0; p < 2; ++p) pfB[p] = *(const uint2*)(pB + glo[p]);
        }

        process(SA, aA_cur);
        if (hasB) process(SB, aB_cur);

        // rotate pipeline registers
        aA_cur = aA_n; aB_cur = aB_n;
        sa_nxt = sa_n2; sb_nxt = sb_n2;
        eA1 = eA2; eB1 = eB2;
    }

    // single non-atomic bf16 store of this third-node's aggregate
#pragma unroll
    for (int mt = 0; mt < 2; ++mt)
#pragma unroll
        for (int g2 = 0; g2 < 4; ++g2) {
            const int gr = mh * 32 + mt * 16 + quad * 4 + g2;  // = l*8 + b
            const int b = gr & 7, l = gr >> 3;
            agg[(i * 96 + b * 12 + l) * 64 + n] = fbf(accN[mt][g2]);
        }
}

// ---------------------------------------------------------------------------
// GRU2 (R8 version): gi AND gh via MFMA; x = relu(agg bf16); 16 seqs /
// 4 waves per block; H+X ping-pong; next x prefetched under MFMAs.
// Weight frags precomputed AND gate-row pre-scaled (mega bx 5501).
// ---------------------------------------------------------------------------
__global__ __launch_bounds__(256) void gru2_kernel(
    const ushort_t* __restrict__ agg, const ushort_t* __restrict__ g2frag,
    const float* __restrict__ bih, const float* __restrict__ bhh,
    float* __restrict__ h2out)
{
    __shared__ ushort_t H[2][16][SST] __attribute__((aligned(16)));
    __shared__ ushort_t X[2][16][SST] __attribute__((aligned(16)));

    const int tid = threadIdx.x;
    const int nw = tid >> 6;
    const int c = tid & 15;
    const int quad = (tid >> 4) & 3;
    const int j = nw * 16 + c;
    const int s0 = blockIdx.x * 16;
    const int sl = tid >> 3, k0 = (tid & 7) * 8;

    if (tid < 128) *(uint4*)&H[0][tid >> 3][(tid & 7) * 8] = uint4{0, 0, 0, 0};

    bf16x8 Bh[3][2], Bi[3][2];
    float bi[3], bh[3];
#pragma unroll
    for (int g = 0; g < 3; ++g) {
        const float sc = (g == 2) ? 2.f * LOG2E : LOG2E;
        const int row = g * 64 + j;
        bi[g] = bih[row] * sc; bh[g] = bhh[row] * sc;
#pragma unroll
        for (int ks = 0; ks < 2; ++ks) {
            Bh[g][ks] = *(const bf16x8*)(g2frag + (((g * 2 + ks) * 2 + 0) * 256 + tid) * 8);
            Bi[g][ks] = *(const bf16x8*)(g2frag + (((g * 2 + ks) * 2 + 1) * 256 + tid) * 8);
        }
    }

    float hold[4];
#pragma unroll
    for (int rg = 0; rg < 4; ++rg) hold[rg] = 0.f;

    if (tid < 128) {
        ushort_t xr[8];
        *(uint4*)xr = *(const uint4*)(agg + (s0 + sl) * (LSEQ * HDIM) + k0);
        ushort_t xs[8];
#pragma unroll
        for (int q = 0; q < 8; ++q) xs[q] = (xr[q] & 0x8000u) ? (ushort_t)0 : xr[q];
        *(uint4*)&X[0][sl][k0] = *(uint4*)xs;
    }

    for (int t = 0; t < LSEQ; ++t) {
        __syncthreads();
        const int rb = t & 1, wb = 1 - rb;
        bf16x8 ah0 = *(const bf16x8*)&H[rb][c][quad * 8];
        bf16x8 ah1 = *(const bf16x8*)&H[rb][c][32 + quad * 8];
        bf16x8 ax0 = *(const bf16x8*)&X[rb][c][quad * 8];
        bf16x8 ax1 = *(const bf16x8*)&X[rb][c][32 + quad * 8];

        ushort_t xr[8];
        if (t < LSEQ - 1 && tid < 128)
            *(uint4*)xr = *(const uint4*)(agg + (s0 + sl) * (LSEQ * HDIM) +
                                          (t + 1) * HDIM + k0);

        f32x4 gh[3], gi[3];
#pragma unroll
        for (int g = 0; g < 3; ++g) {
            f32x4 acc = {0.f, 0.f, 0.f, 0.f};
            acc = __builtin_amdgcn_mfma_f32_16x16x32_bf16(ah0, Bh[g][0], acc, 0, 0, 0);
            acc = __builtin_amdgcn_mfma_f32_16x16x32_bf16(ah1, Bh[g][1], acc, 0, 0, 0);
            gh[g] = acc;
            f32x4 acc2 = {0.f, 0.f, 0.f, 0.f};
            acc2 = __builtin_amdgcn_mfma_f32_16x16x32_bf16(ax0, Bi[g][0], acc2, 0, 0, 0);
            acc2 = __builtin_amdgcn_mfma_f32_16x16x32_bf16(ax1, Bi[g][1], acc2, 0, 0, 0);
            gi[g] = acc2;
        }
#pragma unroll
        for (int rg = 0; rg < 4; ++rg) {
            const int sloc = quad * 4 + rg;
            float r = sigm2(bi[0] + gi[0][rg] + bh[0] + gh[0][rg]);
            float z = sigm2(bi[1] + gi[1][rg] + bh[1] + gh[1][rg]);
            float n = tanh2(bi[2] + gi[2][rg] + r * (bh[2] + gh[2][rg]));
            float hv = (1.f - z) * n + z * hold[rg];
            hold[rg] = hv;
            H[wb][sloc][j] = fbf(hv);
        }
        if (t < LSEQ - 1 && tid < 128) {
            ushort_t xs[8];
#pragma unroll
            for (int q = 0; q < 8; ++q) xs[q] = (xr[q] & 0x8000u) ? (ushort_t)0 : xr[q];
            *(uint4*)&X[wb][sl][k0] = *(uint4*)xs;
        }
    }
#pragma unroll
    for (int rg = 0; rg < 4; ++rg) {
        const int sloc = quad * 4 + rg;
        h2out[(s0 + sloc) * HDIM + j] = hold[rg];
    }
}

extern "C" void kernel_launch(void* const* d_in, const int* in_sizes, int n_in,
                              void* d_out, int out_size, void* d_ws, size_t ws_size,
                              hipStream_t stream)
{
    const float* data     = (const float*)d_in[0];
    const float* features = (const float*)d_in[1];
    const int*   edges    = (const int*)d_in[2];
    const float* Wih1     = (const float*)d_in[3];
    const float* Whh1     = (const float*)d_in[4];
    const float* bih1     = (const float*)d_in[5];
    const float* bhh1     = (const float*)d_in[6];
    const float* W1       = (const float*)d_in[7];
    const float* b1       = (const float*)d_in[8];
    const float* W2       = (const float*)d_in[9];
    const float* b2       = (const float*)d_in[10];
    const float* W3       = (const float*)d_in[11];
    const float* b3       = (const float*)d_in[12];
    const float* Wih2     = (const float*)d_in[13];
    const float* Whh2     = (const float*)d_in[14];
    const float* bih2     = (const float*)d_in[15];
    const float* bhh2     = (const float*)d_in[16];

    float*    out  = (float*)d_out;
    char*     ws   = (char*)d_ws;
    ushort_t* out1 = (ushort_t*)ws;                    // bf16 intermediate
    ushort_t* agg  = (ushort_t*)(ws + OUT1_BYTES);     // bf16 GAT output
    int*      meta = (int*)(ws + OUT1_BYTES + AGG_BYTES);
    int*   degree   = meta;                                 // [2000]
    int*   rowstart = meta + NNODE;                         // [2000]
    int2*  pairs    = (int2*)(meta + 2 * NNODE);            // [16000] (src,eid)
    int*   order    = meta + 2 * NNODE + 2 * NEDGE;         // [2000]
    float* alphas   = (float*)(meta + 3 * NNODE + 2 * NEDGE);  // [36000]
    ushort_t* wfrag  = (ushort_t*)((char*)alphas + 36000 * 4); // [24576] 16B-aligned
    ushort_t* g2frag = wfrag + WFRAG_ELEMS;                    // [24576]
    int*      rank_  = (int*)(g2frag + G2FRAG_ELEMS);          // [16000]

    // 3 dispatches: mega (gru1 || csr || alpha || frag-precompute), gat, gru2.
    mega_kernel<<<1001 + 4500 + 1, 256, 0, stream>>>(
        data, Wih1, Whh1, bih1, bhh1, out1, out,
        edges, degree, rowstart, pairs, order, rank_,
        features, W1, b1, W2, b2, alphas,
        W3, b3, Wih2, Whh2, wfrag, g2frag);
    gat_csr_kernel<<<dim3(NNODE, 3), 256, 0, stream>>>(out1, degree, rowstart, pairs,
                                                       order, alphas, wfrag, agg);
    gru2_kernel<<<NSEQ / 16, 256, 0, stream>>>(agg, g2frag, bih2, bhh2,
                                               out + NNODE * NB * HDIM);
}